// Round 4
// baseline (556.809 us; speedup 1.0000x reference)
//
#include <hip/hip_runtime.h>
#include <hip/hip_fp16.h>
#include <math.h>

#define NN 50000
#define EE 800000
#define FIN 128
#define NH 5
#define HC 160
#define NG 64
#define CH 128        // fast-path max items per node (deg <= 127)
#define NB 160        // sort blocks
#define EPB 5000      // edges per sort block (NB*EPB == EE)
#define NW 12500      // packed histogram words (4 byte-bins per word)
#define ALS8 8        // padded stride for al_s (float4 + float loads)
#define LOG2E 1.4426950408889634f

__device__ __forceinline__ float lrelu(float x, float s) { return x >= 0.f ? x : s * x; }

// unpack 4 consecutive fp16 (8B) to float4
__device__ __forceinline__ float4 h8_to_f4(uint2 u) {
    __half2 a = *reinterpret_cast<__half2*>(&u.x);
    __half2 b = *reinterpret_cast<__half2*>(&u.y);
    float2 fa = __half22float2(a), fb = __half22float2(b);
    return make_float4(fa.x, fa.y, fb.x, fb.y);
}

// ---------------- psum zero + per-graph node counts + per-layer s[h] (merged preps)
__global__ void prep_kernel(const int* __restrict__ batch, float* psum, int* gcnt,
                            const float* we1, const float* ae1,
                            const float* we2, const float* ae2, float* s_out) {
    int i = blockIdx.x * 256 + threadIdx.x;
    if (i < NG * HC) psum[i] = 0.f;
    if (i < NG) {
        int lo = 0, hi = NN;
        while (lo < hi) { int m = (lo + hi) >> 1; if (batch[m] < i) lo = m + 1; else hi = m; }
        int s = lo;
        lo = 0; hi = NN;
        int g1 = i + 1;
        while (lo < hi) { int m = (lo + hi) >> 1; if (batch[m] < g1) lo = m + 1; else hi = m; }
        gcnt[i] = lo - s;
    }
    if (i < 10) {
        const float* we = (i < 5) ? we1 : we2;
        const float* ae = (i < 5) ? ae1 : ae2;
        int h = i % 5;
        float s = 0.f;
        for (int c = 0; c < 32; c++) s += we[h * 32 + c] * ae[h * 32 + c];
        s_out[i] = s * LOG2E;          // exp2-domain
    }
}

// ---------------- per-block LDS histogram of dst (byte-packed, no global atomics)
__global__ __launch_bounds__(256) void hist_kernel(const int* __restrict__ ei,
                                                   unsigned* __restrict__ hist_g) {
    __shared__ unsigned lh[NW];
    int b = blockIdx.x, tid = threadIdx.x;
    for (int w = tid; w < NW; w += 256) lh[w] = 0;
    __syncthreads();
    const int* dstp = ei + EE + b * EPB;
    for (int i = tid; i < EPB; i += 256) {
        int d = dstp[i];
        atomicAdd(&lh[d >> 2], 1u << ((d & 3) * 8));
    }
    __syncthreads();
    unsigned* outp = hist_g + (size_t)b * NW;
    for (int w = tid; w < NW; w += 256) outp[w] = lh[w];
}

// ---------------- column scan over blocks: per-(block,bin) base + total deg
__global__ void sscan_kernel(const unsigned* __restrict__ hist_g,
                             unsigned short* __restrict__ base_g, int* __restrict__ deg) {
    int w = blockIdx.x * 256 + threadIdx.x;
    if (w >= NW) return;
    unsigned r0 = 0, r1 = 0, r2 = 0, r3 = 0;
    for (int b = 0; b < NB; b++) {
        unsigned x = hist_g[(size_t)b * NW + w];
        uint2 st;
        st.x = r0 | (r1 << 16);
        st.y = r2 | (r3 << 16);
        *reinterpret_cast<uint2*>(&base_g[(size_t)b * NN + 4 * w]) = st;
        r0 += x & 0xffu; r1 += (x >> 8) & 0xffu; r2 += (x >> 16) & 0xffu; r3 += (x >> 24) & 0xffu;
    }
    uint4 dv; dv.x = r0; dv.y = r1; dv.z = r2; dv.w = r3;
    *reinterpret_cast<uint4*>(&deg[4 * w]) = dv;
}

// ------------------------------------------------------- 3-phase parallel scan
__global__ void scan1_kernel(const int* __restrict__ deg, int* bsum) {
    __shared__ int ws[4];
    int tid = threadIdx.x, lane = tid & 63, wid = tid >> 6;
    int i = blockIdx.x * 256 + tid;
    int v = (i < NN) ? deg[i] : 0;
    for (int o = 32; o >= 1; o >>= 1) v += __shfl_down(v, o, 64);
    if (lane == 0) ws[wid] = v;
    __syncthreads();
    if (tid == 0) bsum[blockIdx.x] = ws[0] + ws[1] + ws[2] + ws[3];
}

__global__ void scan2_kernel(int* bsum, int* boff) {
    __shared__ int ws[4];
    int tid = threadIdx.x, lane = tid & 63, wid = tid >> 6;
    int v = (tid < 196) ? bsum[tid] : 0;
    int x = v;
    for (int o = 1; o < 64; o <<= 1) {
        int t = __shfl_up(x, o, 64);
        if (lane >= o) x += t;
    }
    if (lane == 63) ws[wid] = x;
    __syncthreads();
    if (tid == 0) {
        int acc = 0;
        for (int w = 0; w < 4; w++) { int t = ws[w]; ws[w] = acc; acc += t; }
    }
    __syncthreads();
    if (tid < 196) boff[tid] = x + ws[wid] - v;
}

__global__ void scan3_kernel(const int* __restrict__ deg, const int* __restrict__ boff,
                             int* off) {
    __shared__ int ws[4];
    int tid = threadIdx.x, lane = tid & 63, wid = tid >> 6;
    int i = blockIdx.x * 256 + tid;
    int v = (i < NN) ? deg[i] : 0;
    int x = v;
    for (int o = 1; o < 64; o <<= 1) {
        int t = __shfl_up(x, o, 64);
        if (lane >= o) x += t;
    }
    if (lane == 63) ws[wid] = x;
    __syncthreads();
    if (tid == 0) {
        int acc = 0;
        for (int w = 0; w < 4; w++) { int t = ws[w]; ws[w] = acc; acc += t; }
    }
    __syncthreads();
    int incl = x + ws[wid] + boff[blockIdx.x];
    if (i < NN) off[i + 1] = incl;
    if (i == 0) off[0] = 0;
}

// ---------------- rank via LDS + write packed edge record (no global atomics)
__global__ __launch_bounds__(256) void scatter_kernel(const int* __restrict__ ei,
                                                      const float* __restrict__ ea,
                                                      const unsigned short* __restrict__ base_g,
                                                      const int* __restrict__ soff,
                                                      uint4* __restrict__ erec) {
    __shared__ unsigned lc[NW];
    int b = blockIdx.x, tid = threadIdx.x;
    for (int w = tid; w < NW; w += 256) lc[w] = 0;
    __syncthreads();
    int e0 = b * EPB;
    const unsigned short* brow = base_g + (size_t)b * NN;
    for (int i = tid; i < EPB; i += 256) {
        int e = e0 + i;
        int d = ei[EE + e];
        int sh = (d & 3) * 8;
        unsigned old = atomicAdd(&lc[d >> 2], 1u << sh);
        int r = (int)((old >> sh) & 0xffu);
        int pos = soff[d] + (int)brow[d] + r;
        uint4 rec;
        rec.x = (unsigned)ei[e];
        rec.y = (unsigned)e;
        rec.z = __float_as_uint(ea[e]);
        rec.w = 0;
        erec[pos] = rec;
    }
}

#define ROWFMA(rr, av) \
    acc[rr][0] += (av) * b0; acc[rr][1] += (av) * b1; acc[rr][2] += (av) * b2; \
    acc[rr][3] += (av) * b3; acc[rr][4] += (av) * b4;

// ---------------- h = A @ W  (K = 128 or 160, A fp32 or fp16): 64 rows x 160 cols,
//                  8x5 register tile; reg-double-buffered staging; fused att dots.
//                  h stored fp16; al_s/al_d pre-scaled by LOG2E (exp2-domain).
template <int K, typename AT>
__global__ __launch_bounds__(256) void gemm_kernel(const AT* __restrict__ A,
                                                   const float* __restrict__ W,
                                                   const float* __restrict__ a_s,
                                                   const float* __restrict__ a_d,
                                                   __half* __restrict__ out,
                                                   float* __restrict__ al_s,
                                                   float* __restrict__ al_d) {
    __shared__ float As[32 * 64];    // [k][row]
    __shared__ float Bs[32 * 160];   // [k][c]
    __shared__ float hs[32 * 168];   // [row32][h*33 + c]  (head-padded)
    const int tid = threadIdx.x;
    const int base = blockIdx.x * 64;
    const int tc = tid & 31, tr = tid >> 5;       // col-thread, row-thread
    const int srow = tid >> 2, skq = tid & 3;     // staging map
    const bool rowok = (base + srow) < NN;
    const AT* arow = A + (size_t)(base + srow) * K;

    float acc[8][5];
#pragma unroll
    for (int r = 0; r < 8; r++)
#pragma unroll
        for (int c = 0; c < 5; c++) acc[r][c] = 0.f;

    auto loadA = [&](int k0, float4& a0, float4& a1) {
        a0 = make_float4(0.f, 0.f, 0.f, 0.f); a1 = a0;
        if (rowok) {
            if constexpr (sizeof(AT) == 4) {
                a0 = *reinterpret_cast<const float4*>(arow + k0 + skq * 4);
                a1 = *reinterpret_cast<const float4*>(arow + k0 + 16 + skq * 4);
            } else {
                uint2 u0 = *reinterpret_cast<const uint2*>(arow + k0 + skq * 4);
                uint2 u1 = *reinterpret_cast<const uint2*>(arow + k0 + 16 + skq * 4);
                a0 = h8_to_f4(u0); a1 = h8_to_f4(u1);
            }
        }
    };
    auto loadB = [&](int k0, float4 (&bv)[5]) {
#pragma unroll
        for (int i = 0; i < 5; i++) {
            int f = tid + 256 * i;
            int kk = f / 40, c4 = f - kk * 40;
            bv[i] = *reinterpret_cast<const float4*>(&W[(size_t)(k0 + kk) * HC + c4 * 4]);
        }
    };

    float4 pa0, pa1, pb[5];
    loadA(0, pa0, pa1);
    loadB(0, pb);

    constexpr int NT = K / 32;
    for (int t = 0; t < NT; t++) {
        // ---- write staged regs to LDS
        As[(skq * 4 + 0) * 64 + srow] = pa0.x;
        As[(skq * 4 + 1) * 64 + srow] = pa0.y;
        As[(skq * 4 + 2) * 64 + srow] = pa0.z;
        As[(skq * 4 + 3) * 64 + srow] = pa0.w;
        As[(skq * 4 + 16) * 64 + srow] = pa1.x;
        As[(skq * 4 + 17) * 64 + srow] = pa1.y;
        As[(skq * 4 + 18) * 64 + srow] = pa1.z;
        As[(skq * 4 + 19) * 64 + srow] = pa1.w;
#pragma unroll
        for (int i = 0; i < 5; i++) {
            int f = tid + 256 * i;
            int kk = f / 40, c4 = f - kk * 40;
            *reinterpret_cast<float4*>(&Bs[kk * 160 + c4 * 4]) = pb[i];
        }
        __syncthreads();
        if (t + 1 < NT) {                 // prefetch next tile (overlaps compute)
            loadA((t + 1) * 32, pa0, pa1);
            loadB((t + 1) * 32, pb);
        }
#pragma unroll 8
        for (int k = 0; k < 32; k++) {
            const float4 a0 = *reinterpret_cast<const float4*>(&As[k * 64 + tr * 8]);
            const float4 a1 = *reinterpret_cast<const float4*>(&As[k * 64 + tr * 8 + 4]);
            const float b0 = Bs[k * 160 + tc];
            const float b1 = Bs[k * 160 + tc + 32];
            const float b2 = Bs[k * 160 + tc + 64];
            const float b3 = Bs[k * 160 + tc + 96];
            const float b4 = Bs[k * 160 + tc + 128];
            ROWFMA(0, a0.x) ROWFMA(1, a0.y) ROWFMA(2, a0.z) ROWFMA(3, a0.w)
            ROWFMA(4, a1.x) ROWFMA(5, a1.y) ROWFMA(6, a1.z) ROWFMA(7, a1.w)
        }
        __syncthreads();
    }
    // ---- store h (fp16)
#pragma unroll
    for (int r = 0; r < 8; r++) {
        int grow = base + tr * 8 + r;
        if (grow < NN) {
            __half* op = out + (size_t)grow * HC + tc;
            op[0]   = __float2half(acc[r][0]);
            op[32]  = __float2half(acc[r][1]);
            op[64]  = __float2half(acc[r][2]);
            op[96]  = __float2half(acc[r][3]);
            op[128] = __float2half(acc[r][4]);
        }
    }
    // ---- att-dot epilogue: two halves of 32 rows via hs (fp32 accs)
    for (int half = 0; half < 2; half++) {
        __syncthreads();
        if ((tr >> 2) == half) {
            int r32 = (tr & 3) * 8;
#pragma unroll
            for (int r = 0; r < 8; r++)
#pragma unroll
                for (int ci = 0; ci < 5; ci++)
                    hs[(r32 + r) * 168 + ci * 33 + tc] = acc[r][ci];
        }
        __syncthreads();
        for (int t = tid; t < 320; t += 256) {
            int row32 = t / 10;
            int rem = t - row32 * 10;
            int h = rem >> 1, sd = rem & 1;
            int grow = base + half * 32 + row32;
            if (grow < NN) {
                const float* av = (sd ? a_d : a_s) + h * 32;
                const float* hp = &hs[row32 * 168 + h * 33];
                float s = 0.f;
#pragma unroll
                for (int c = 0; c < 32; c++) s += hp[c] * av[c];
                s *= LOG2E;                       // exp2-domain logits
                if (sd) al_d[(size_t)grow * NH + h] = s;
                else    al_s[(size_t)grow * ALS8 + h] = s;
            }
        }
    }
}

// ------------- per-node (one WAVE per node, 4 nodes per block): segment softmax
//               (exp2-domain) + weighted fp16 gather + bias/lrelu/LN -> fp16 x_out.
//               Exactly ONE __syncthreads on both paths.
__global__ __launch_bounds__(256, 8) void aggregate_kernel(
    const int* __restrict__ soff, const uint4* __restrict__ erec,
    const __half* __restrict__ hfeat, const float* __restrict__ als,
    const float* __restrict__ al_d, const float* __restrict__ s_e,
    const float* __restrict__ bias, const float* __restrict__ g_ln,
    const float* __restrict__ b_ln,
    float* __restrict__ alpha_out, __half* __restrict__ x_out) {
    const int wave = threadIdx.x >> 6;
    const int lane = threadIdx.x & 63;
    const int n = blockIdx.x * 4 + wave;
    __shared__ float w_sh_all[4][CH * NH];
    __shared__ int ioff_all[4][CH];      // byte offsets into hfeat (src*HC*2)
    float* w_sh = w_sh_all[wave];
    int* ioff_sh = ioff_all[wave];

    const int s0 = soff[n];
    const int deg = soff[n + 1] - s0;
    const int items = deg + 1;

    float adr[NH], ser[NH];
#pragma unroll
    for (int h = 0; h < NH; h++) { adr[h] = al_d[n * NH + h]; ser[h] = s_e[h]; }

    const int c0 = 4 * lane;      // lanes 0..39 own channels c0..c0+3
    const int hd = lane >> 3;     // head for those channels (valid for lane<40)
    float4 acc = make_float4(0.f, 0.f, 0.f, 0.f);

    if (items <= CH) {
        // ---- pass A: logits into registers (2 tiles x 5 heads), per-head max, ea sum
        float rw[2][NH];
        float lm[NH];
#pragma unroll
        for (int h = 0; h < NH; h++) lm[h] = -3.0e38f;
        float eas = 0.f;
        int myy[2];
#pragma unroll
        for (int t = 0; t < 2; t++) {
            int i = lane + 64 * t;
            if (i < deg) {
                uint4 rec = erec[s0 + i];
                int src = (int)rec.x;
                float eav = __uint_as_float(rec.z);
                ioff_sh[i] = src * (HC * 2);
                myy[t] = (int)rec.y;
                eas += eav;
                const float* ap = als + (size_t)src * ALS8;
                float4 a4 = *reinterpret_cast<const float4*>(ap);
                float a5 = ap[4];
                float asv[5] = {a4.x, a4.y, a4.z, a4.w, a5};
#pragma unroll
                for (int h = 0; h < NH; h++) {
                    float r = lrelu(asv[h] + adr[h] + eav * ser[h], 0.2f);
                    rw[t][h] = r;
                    lm[h] = fmaxf(lm[h], r);
                }
            }
        }
#pragma unroll
        for (int o = 1; o < 64; o <<= 1) {
#pragma unroll
            for (int h = 0; h < NH; h++) lm[h] = fmaxf(lm[h], __shfl_xor(lm[h], o, 64));
            eas += __shfl_xor(eas, o, 64);
        }
        float emean = eas / fmaxf((float)deg, 1.f);
        float m[NH], rs[NH];
        {
            const float* ap = als + (size_t)n * ALS8;
            float4 a4 = *reinterpret_cast<const float4*>(ap);
            float a5 = ap[4];
            float asv[5] = {a4.x, a4.y, a4.z, a4.w, a5};
#pragma unroll
            for (int h = 0; h < NH; h++) {
                rs[h] = lrelu(asv[h] + adr[h] + emean * ser[h], 0.2f);
                m[h] = fmaxf(lm[h], rs[h]);
            }
        }
        // ---- pass B: exp2 in registers + sum
        float ls[NH] = {0.f, 0.f, 0.f, 0.f, 0.f};
#pragma unroll
        for (int t = 0; t < 2; t++) {
            int i = lane + 64 * t;
            if (i < deg) {
#pragma unroll
                for (int h = 0; h < NH; h++) {
                    float w = exp2f(rw[t][h] - m[h]);
                    rw[t][h] = w;
                    ls[h] += w;
                }
            } else if (i == deg) {          // self-loop owner lane
                ioff_sh[i] = n * (HC * 2);
#pragma unroll
                for (int h = 0; h < NH; h++) {
                    float w = exp2f(rs[h] - m[h]);
                    rw[t][h] = w;
                    ls[h] += w;
                }
            }
        }
#pragma unroll
        for (int o = 1; o < 64; o <<= 1) {
#pragma unroll
            for (int h = 0; h < NH; h++) ls[h] += __shfl_xor(ls[h], o, 64);
        }
        float dinv[NH];
#pragma unroll
        for (int h = 0; h < NH; h++) dinv[h] = 1.f / ls[h];
        // ---- normalize: final weights -> LDS + alpha writeback
#pragma unroll
        for (int t = 0; t < 2; t++) {
            int i = lane + 64 * t;
            if (i < items) {
                int opos = (i < deg) ? myy[t] : (EE + n);
#pragma unroll
                for (int h = 0; h < NH; h++) {
                    float w = rw[t][h] * dinv[h];
                    w_sh[i * NH + h] = w;
                    alpha_out[(size_t)opos * NH + h] = w;
                }
            }
        }
        __syncthreads();                                   // [barrier #1 of 1]
        // ---- pass C: 4-deep pipelined fp16 gather via precomputed byte offsets
        if (lane < 40) {
            const char* hb = (const char*)hfeat + (size_t)(c0 * 2);
            for (int i0 = 0; i0 < items; i0 += 4) {
                float wv[4];
                uint2 hv[4];
#pragma unroll
                for (int j = 0; j < 4; j++) {
                    int i = i0 + j;
                    bool ok = i < items;
                    int ii = ok ? i : 0;
                    wv[j] = ok ? w_sh[ii * NH + hd] : 0.f;
                    hv[j] = *reinterpret_cast<const uint2*>(hb + (size_t)(unsigned)ioff_sh[ii]);
                }
#pragma unroll
                for (int j = 0; j < 4; j++) {
                    __half2 p0 = *reinterpret_cast<__half2*>(&hv[j].x);
                    __half2 p1 = *reinterpret_cast<__half2*>(&hv[j].y);
                    acc.x += wv[j] * __low2float(p0);
                    acc.y += wv[j] * __high2float(p0);
                    acc.z += wv[j] * __low2float(p1);
                    acc.w += wv[j] * __high2float(p1);
                }
            }
        }
    } else {
        // ---- slow path (deg >= CH): streaming recompute, no LDS
        float lm[NH];
#pragma unroll
        for (int h = 0; h < NH; h++) lm[h] = -3.0e38f;
        float eas = 0.f;
        for (int i = lane; i < deg; i += 64) {
            uint4 rec = erec[s0 + i];
            int src = (int)rec.x;
            float eav = __uint_as_float(rec.z);
            eas += eav;
            const float* ap = als + (size_t)src * ALS8;
            float4 a4 = *reinterpret_cast<const float4*>(ap);
            float a5 = ap[4];
            float asv[5] = {a4.x, a4.y, a4.z, a4.w, a5};
#pragma unroll
            for (int h = 0; h < NH; h++) {
                float r = lrelu(asv[h] + adr[h] + eav * ser[h], 0.2f);
                lm[h] = fmaxf(lm[h], r);
            }
        }
#pragma unroll
        for (int o = 1; o < 64; o <<= 1) {
#pragma unroll
            for (int h = 0; h < NH; h++) lm[h] = fmaxf(lm[h], __shfl_xor(lm[h], o, 64));
            eas += __shfl_xor(eas, o, 64);
        }
        float emean = eas / fmaxf((float)deg, 1.f);
        float m[NH], rs[NH];
        {
            const float* ap = als + (size_t)n * ALS8;
#pragma unroll
            for (int h = 0; h < NH; h++) {
                rs[h] = lrelu(ap[h] + adr[h] + emean * ser[h], 0.2f);
                m[h] = fmaxf(lm[h], rs[h]);
            }
        }
        float ls[NH] = {0.f, 0.f, 0.f, 0.f, 0.f};
        for (int i = lane; i < items; i += 64) {
            int src; float eav;
            if (i < deg) { uint4 rec = erec[s0 + i]; src = (int)rec.x; eav = __uint_as_float(rec.z); }
            else         { src = n; eav = emean; }
            const float* ap = als + (size_t)src * ALS8;
#pragma unroll
            for (int h = 0; h < NH; h++) {
                float r = lrelu(ap[h] + adr[h] + eav * ser[h], 0.2f);
                ls[h] += exp2f(r - m[h]);
            }
        }
#pragma unroll
        for (int o = 1; o < 64; o <<= 1) {
#pragma unroll
            for (int h = 0; h < NH; h++) ls[h] += __shfl_xor(ls[h], o, 64);
        }
        float dinv[NH];
#pragma unroll
        for (int h = 0; h < NH; h++) dinv[h] = 1.f / ls[h];
        __syncthreads();                                   // [barrier #1 of 1]
        for (int i = lane; i < items; i += 64) {
            int src; float eav; int opos;
            if (i < deg) { uint4 rec = erec[s0 + i]; src = (int)rec.x; eav = __uint_as_float(rec.z); opos = (int)rec.y; }
            else         { src = n; eav = emean; opos = EE + n; }
            const float* ap = als + (size_t)src * ALS8;
#pragma unroll
            for (int h = 0; h < NH; h++) {
                float r = lrelu(ap[h] + adr[h] + eav * ser[h], 0.2f);
                alpha_out[(size_t)opos * NH + h] = exp2f(r - m[h]) * dinv[h];
            }
        }
        if (lane < 40) {
            for (int i = 0; i < items; i++) {
                int src; float eav;
                if (i < deg) { uint4 rec = erec[s0 + i]; src = (int)rec.x; eav = __uint_as_float(rec.z); }
                else         { src = n; eav = emean; }
                float r = lrelu(als[(size_t)src * ALS8 + hd] + adr[hd] + eav * ser[hd], 0.2f);
                float w = exp2f(r - m[hd]) * dinv[hd];
                uint2 hv = *reinterpret_cast<const uint2*>(
                    &hfeat[(size_t)src * HC + c0]);
                float4 hf = h8_to_f4(hv);
                acc.x += w * hf.x; acc.y += w * hf.y;
                acc.z += w * hf.z; acc.w += w * hf.w;
            }
        }
    }

    // ---- bias + lrelu + fused LayerNorm across 160 channels (wave butterfly)
    float4 v = make_float4(0.f, 0.f, 0.f, 0.f);
    float p1 = 0.f, p2 = 0.f;
    if (lane < 40) {
        const float4 b4 = *reinterpret_cast<const float4*>(&bias[c0]);
        v.x = lrelu(acc.x + b4.x, 0.01f);
        v.y = lrelu(acc.y + b4.y, 0.01f);
        v.z = lrelu(acc.z + b4.z, 0.01f);
        v.w = lrelu(acc.w + b4.w, 0.01f);
        p1 = v.x + v.y + v.z + v.w;
        p2 = v.x * v.x + v.y * v.y + v.z * v.z + v.w * v.w;
    }
#pragma unroll
    for (int o = 1; o < 64; o <<= 1) {
        p1 += __shfl_xor(p1, o, 64);
        p2 += __shfl_xor(p2, o, 64);
    }
    float mean = p1 * (1.f / (float)HC);
    float var = p2 * (1.f / (float)HC) - mean * mean;
    float rstd = rsqrtf(var + 1e-5f);
    if (lane < 40) {
        const float4 g4 = *reinterpret_cast<const float4*>(&g_ln[c0]);
        const float4 bb = *reinterpret_cast<const float4*>(&b_ln[c0]);
        float ox = (v.x - mean) * rstd * g4.x + bb.x;
        float oy = (v.y - mean) * rstd * g4.y + bb.y;
        float oz = (v.z - mean) * rstd * g4.z + bb.z;
        float ow = (v.w - mean) * rstd * g4.w + bb.w;
        __half2 h01 = __floats2half2_rn(ox, oy);
        __half2 h23 = __floats2half2_rn(oz, ow);
        uint2 st;
        st.x = *reinterpret_cast<unsigned*>(&h01);
        st.y = *reinterpret_cast<unsigned*>(&h23);
        *reinterpret_cast<uint2*>(&x_out[(size_t)n * HC + c0]) = st;
    }
}

// -------- x3 = lrelu(x2 @ mw + mb) (x2 fp16); reg-dbuf; fused pooled sums
__global__ __launch_bounds__(256) void gemm3_kernel(const __half* __restrict__ A,
                                                    const float* __restrict__ W,
                                                    const float* __restrict__ bias,
                                                    const int* __restrict__ batch,
                                                    float* __restrict__ x3,
                                                    float* __restrict__ psum) {
    __shared__ float As[32 * 64];
    __shared__ float Bs[32 * 160];
    __shared__ int bt[64];
    const int tid = threadIdx.x;
    const int base = blockIdx.x * 64;
    const int tc = tid & 31, tr = tid >> 5;
    const int srow = tid >> 2, skq = tid & 3;
    const bool rowok = (base + srow) < NN;
    const __half* arow = A + (size_t)(base + srow) * HC;

    float acc[8][5];
#pragma unroll
    for (int r = 0; r < 8; r++)
#pragma unroll
        for (int c = 0; c < 5; c++) acc[r][c] = 0.f;

    auto loadA = [&](int k0, float4& a0, float4& a1) {
        a0 = make_float4(0.f, 0.f, 0.f, 0.f); a1 = a0;
        if (rowok) {
            uint2 u0 = *reinterpret_cast<const uint2*>(arow + k0 + skq * 4);
            uint2 u1 = *reinterpret_cast<const uint2*>(arow + k0 + 16 + skq * 4);
            a0 = h8_to_f4(u0); a1 = h8_to_f4(u1);
        }
    };
    auto loadB = [&](int k0, float4 (&bv)[5]) {
#pragma unroll
        for (int i = 0; i < 5; i++) {
            int f = tid + 256 * i;
            int kk = f / 40, c4 = f - kk * 40;
            bv[i] = *reinterpret_cast<const float4*>(&W[(size_t)(k0 + kk) * HC + c4 * 4]);
        }
    };

    float4 pa0, pa1, pb[5];
    loadA(0, pa0, pa1);
    loadB(0, pb);
    if (tid < 64) bt[tid] = batch[(base + tid < NN) ? (base + tid) : (NN - 1)];

    for (int t = 0; t < 5; t++) {
        As[(skq * 4 + 0) * 64 + srow] = pa0.x;
        As[(skq * 4 + 1) * 64 + srow] = pa0.y;
        As[(skq * 4 + 2) * 64 + srow] = pa0.z;
        As[(skq * 4 + 3) * 64 + srow] = pa0.w;
        As[(skq * 4 + 16) * 64 + srow] = pa1.x;
        As[(skq * 4 + 17) * 64 + srow] = pa1.y;
        As[(skq * 4 + 18) * 64 + srow] = pa1.z;
        As[(skq * 4 + 19) * 64 + srow] = pa1.w;
#pragma unroll
        for (int i = 0; i < 5; i++) {
            int f = tid + 256 * i;
            int kk = f / 40, c4 = f - kk * 40;
            *reinterpret_cast<float4*>(&Bs[kk * 160 + c4 * 4]) = pb[i];
        }
        __syncthreads();
        if (t + 1 < 5) {
            loadA((t + 1) * 32, pa0, pa1);
            loadB((t + 1) * 32, pb);
        }
#pragma unroll 8
        for (int k = 0; k < 32; k++) {
            const float4 a0 = *reinterpret_cast<const float4*>(&As[k * 64 + tr * 8]);
            const float4 a1 = *reinterpret_cast<const float4*>(&As[k * 64 + tr * 8 + 4]);
            const float b0 = Bs[k * 160 + tc];
            const float b1 = Bs[k * 160 + tc + 32];
            const float b2 = Bs[k * 160 + tc + 64];
            const float b3 = Bs[k * 160 + tc + 96];
            const float b4 = Bs[k * 160 + tc + 128];
            ROWFMA(0, a0.x) ROWFMA(1, a0.y) ROWFMA(2, a0.z) ROWFMA(3, a0.w)
            ROWFMA(4, a1.x) ROWFMA(5, a1.y) ROWFMA(6, a1.z) ROWFMA(7, a1.w)
        }
        __syncthreads();
    }
    float bj[5];
#pragma unroll
    for (int ci = 0; ci < 5; ci++) bj[ci] = bias[tc + 32 * ci];
    float run[5] = {0.f, 0.f, 0.f, 0.f, 0.f};
    int g = bt[tr * 8];
#pragma unroll
    for (int r = 0; r < 8; r++) {
        int grow = base + tr * 8 + r;
        bool ok = grow < NN;
        float vv[5];
#pragma unroll
        for (int ci = 0; ci < 5; ci++) vv[ci] = lrelu(acc[r][ci] + bj[ci], 0.01f);
        if (ok) {
            float* op = x3 + (size_t)grow * HC + tc;
            op[0] = vv[0]; op[32] = vv[1]; op[64] = vv[2]; op[96] = vv[3]; op[128] = vv[4];
        }
        int gb = bt[tr * 8 + r];
        if (gb != g) {
#pragma unroll
            for (int ci = 0; ci < 5; ci++) {
                atomicAdd(&psum[g * HC + tc + 32 * ci], run[ci]);
                run[ci] = 0.f;
            }
            g = gb;
        }
        if (ok) {
#pragma unroll
            for (int ci = 0; ci < 5; ci++) run[ci] += vv[ci];
        }
    }
#pragma unroll
    for (int ci = 0; ci < 5; ci++) atomicAdd(&psum[g * HC + tc + 32 * ci], run[ci]);
}

__global__ void pooldiv_kernel(const float* __restrict__ psum, const int* __restrict__ gcnt,
                               float* pooled_out) {
    int i = blockIdx.x * 256 + threadIdx.x;
    if (i < NG * HC) pooled_out[i] = psum[i] / fmaxf((float)gcnt[i / HC], 1.f);
}

// ---------------------------------------------------------------------- launch
extern "C" void kernel_launch(void* const* d_in, const int* in_sizes, int n_in,
                              void* d_out, int out_size, void* d_ws, size_t ws_size,
                              hipStream_t stream) {
    const float* x    = (const float*)d_in[0];
    const int*   ei   = (const int*)d_in[1];
    const float* ea   = (const float*)d_in[2];
    const int*   batch= (const int*)d_in[3];
    const float* w1   = (const float*)d_in[4];
    const float* we1  = (const float*)d_in[5];
    const float* as1  = (const float*)d_in[6];
    const float* ad1  = (const float*)d_in[7];
    const float* ae1  = (const float*)d_in[8];
    const float* b1   = (const float*)d_in[9];
    const float* w2   = (const float*)d_in[10];
    const float* we2  = (const float*)d_in[11];
    const float* as2  = (const float*)d_in[12];
    const float* ad2  = (const float*)d_in[13];
    const float* ae2  = (const float*)d_in[14];
    const float* b2   = (const float*)d_in[15];
    const float* ln1g = (const float*)d_in[16];
    const float* ln1b = (const float*)d_in[17];
    const float* ln2g = (const float*)d_in[18];
    const float* ln2b = (const float*)d_in[19];
    const float* mw   = (const float*)d_in[20];
    const float* mb   = (const float*)d_in[21];

    float* out = (float*)d_out;
    float* pooled_out = out + (size_t)NN * HC;
    float* a1 = pooled_out + NG * HC;
    float* a2 = a1 + (size_t)(EE + NN) * NH;

    char* wp = (char*)d_ws;
    auto alloc = [&](size_t bytes) {
        void* p = (void*)wp;
        wp += (bytes + 255) & ~(size_t)255;
        return p;
    };
    // 32MB region, triple-overlaid in time:
    //   [0..8)   hist_g   (dead after sscan)     -> [0..16)  h fp16
    //   [8..24)  base_g   (dead after scatter)   -> [16..32) x12h fp16
    char* region = (char*)alloc(32 * 1024 * 1024);
    __half* hbuf = (__half*)region;                               // 16 MB fp16 h
    __half* x12h = (__half*)(region + 16 * 1024 * 1024);          // 16 MB fp16 x1/x2
    unsigned*       hist_g = (unsigned*)region;                   // 8 MB
    unsigned short* base_g = (unsigned short*)(region + 8 * 1024 * 1024); // 16 MB
    uint4* erec  = (uint4*)alloc((size_t)EE * 16);       // 12.8 MB
    float* als   = (float*)alloc((size_t)NN * ALS8 * 4); // padded al_s
    float* ald   = (float*)alloc((size_t)NN * NH * 4);
    int*   deg   = (int*)alloc((size_t)NN * 4);
    int*   soff  = (int*)alloc((size_t)(NN + 1) * 4);
    float* sbuf  = (float*)alloc(64);
    float* psum  = (float*)alloc((size_t)NG * HC * 4);
    int*   gcnt  = (int*)alloc((size_t)NG * 4);
    int*   bsum  = (int*)alloc(256 * 4);
    int*   boff  = (int*)alloc(256 * 4);

    prep_kernel<<<40, 256, 0, stream>>>(batch, psum, gcnt, we1, ae1, we2, ae2, sbuf);
    hist_kernel<<<NB, 256, 0, stream>>>(ei, hist_g);
    sscan_kernel<<<49, 256, 0, stream>>>(hist_g, base_g, deg);
    scan1_kernel<<<196, 256, 0, stream>>>(deg, bsum);
    scan2_kernel<<<1, 256, 0, stream>>>(bsum, boff);
    scan3_kernel<<<196, 256, 0, stream>>>(deg, boff, soff);
    scatter_kernel<<<NB, 256, 0, stream>>>(ei, ea, base_g, soff, erec);

    gemm_kernel<128, float><<<782, 256, 0, stream>>>(x, w1, as1, ad1, hbuf, als, ald);
    aggregate_kernel<<<12500, 256, 0, stream>>>(soff, erec, hbuf, als, ald,
                                                sbuf, b1, ln1g, ln1b, a1, x12h);

    gemm_kernel<160, __half><<<782, 256, 0, stream>>>(x12h, w2, as2, ad2, hbuf, als, ald);
    aggregate_kernel<<<12500, 256, 0, stream>>>(soff, erec, hbuf, als, ald,
                                                sbuf + 5, b2, ln2g, ln2b, a2, x12h);

    gemm3_kernel<<<782, 256, 0, stream>>>(x12h, mw, mb, batch, out, psum);
    pooldiv_kernel<<<40, 256, 0, stream>>>(psum, gcnt, pooled_out);
}

// Round 5
// 525.400 us; speedup vs baseline: 1.0598x; 1.0598x over previous
//
#include <hip/hip_runtime.h>
#include <hip/hip_fp16.h>
#include <math.h>

#define NN 50000
#define EE 800000
#define FIN 128
#define NH 5
#define HC 160
#define NG 64
#define CH 128        // fast-path max items per node (deg <= 127)
#define NB 160        // sort blocks
#define EPB 5000      // edges per sort block (NB*EPB == EE)
#define NW 12500      // packed histogram words (4 byte-bins per word)
#define ALS8 8        // padded stride for al_s (float4 + float loads)
#define LOG2E 1.4426950408889634f
#define ASTR 36       // As padded k-stride (16B-aligned float4 rows, conflict-light)

__device__ __forceinline__ float lrelu(float x, float s) { return x >= 0.f ? x : s * x; }

// unpack 4 consecutive fp16 (8B) to float4
__device__ __forceinline__ float4 h8_to_f4(uint2 u) {
    __half2 a = *reinterpret_cast<__half2*>(&u.x);
    __half2 b = *reinterpret_cast<__half2*>(&u.y);
    float2 fa = __half22float2(a), fb = __half22float2(b);
    return make_float4(fa.x, fa.y, fb.x, fb.y);
}

// ---------------- psum zero + per-graph node counts + per-layer s[h] (merged preps)
__global__ void prep_kernel(const int* __restrict__ batch, float* psum, int* gcnt,
                            const float* we1, const float* ae1,
                            const float* we2, const float* ae2, float* s_out) {
    int i = blockIdx.x * 256 + threadIdx.x;
    if (i < NG * HC) psum[i] = 0.f;
    if (i < NG) {
        int lo = 0, hi = NN;
        while (lo < hi) { int m = (lo + hi) >> 1; if (batch[m] < i) lo = m + 1; else hi = m; }
        int s = lo;
        lo = 0; hi = NN;
        int g1 = i + 1;
        while (lo < hi) { int m = (lo + hi) >> 1; if (batch[m] < g1) lo = m + 1; else hi = m; }
        gcnt[i] = lo - s;
    }
    if (i < 10) {
        const float* we = (i < 5) ? we1 : we2;
        const float* ae = (i < 5) ? ae1 : ae2;
        int h = i % 5;
        float s = 0.f;
        for (int c = 0; c < 32; c++) s += we[h * 32 + c] * ae[h * 32 + c];
        s_out[i] = s * LOG2E;          // exp2-domain
    }
}

// ---------------- per-block LDS histogram of dst (byte-packed, no global atomics)
__global__ __launch_bounds__(256) void hist_kernel(const int* __restrict__ ei,
                                                   unsigned* __restrict__ hist_g) {
    __shared__ unsigned lh[NW];
    int b = blockIdx.x, tid = threadIdx.x;
    for (int w = tid; w < NW; w += 256) lh[w] = 0;
    __syncthreads();
    const int* dstp = ei + EE + b * EPB;
    for (int i = tid; i < EPB; i += 256) {
        int d = dstp[i];
        atomicAdd(&lh[d >> 2], 1u << ((d & 3) * 8));
    }
    __syncthreads();
    unsigned* outp = hist_g + (size_t)b * NW;
    for (int w = tid; w < NW; w += 256) outp[w] = lh[w];
}

// ---------------- column scan over blocks: per-(block,bin) base + total deg
__global__ void sscan_kernel(const unsigned* __restrict__ hist_g,
                             unsigned short* __restrict__ base_g, int* __restrict__ deg) {
    int w = blockIdx.x * 256 + threadIdx.x;
    if (w >= NW) return;
    unsigned r0 = 0, r1 = 0, r2 = 0, r3 = 0;
    for (int b = 0; b < NB; b++) {
        unsigned x = hist_g[(size_t)b * NW + w];
        uint2 st;
        st.x = r0 | (r1 << 16);
        st.y = r2 | (r3 << 16);
        *reinterpret_cast<uint2*>(&base_g[(size_t)b * NN + 4 * w]) = st;
        r0 += x & 0xffu; r1 += (x >> 8) & 0xffu; r2 += (x >> 16) & 0xffu; r3 += (x >> 24) & 0xffu;
    }
    uint4 dv; dv.x = r0; dv.y = r1; dv.z = r2; dv.w = r3;
    *reinterpret_cast<uint4*>(&deg[4 * w]) = dv;
}

// ------------------------------------------------------- 3-phase parallel scan
__global__ void scan1_kernel(const int* __restrict__ deg, int* bsum) {
    __shared__ int ws[4];
    int tid = threadIdx.x, lane = tid & 63, wid = tid >> 6;
    int i = blockIdx.x * 256 + tid;
    int v = (i < NN) ? deg[i] : 0;
    for (int o = 32; o >= 1; o >>= 1) v += __shfl_down(v, o, 64);
    if (lane == 0) ws[wid] = v;
    __syncthreads();
    if (tid == 0) bsum[blockIdx.x] = ws[0] + ws[1] + ws[2] + ws[3];
}

__global__ void scan2_kernel(int* bsum, int* boff) {
    __shared__ int ws[4];
    int tid = threadIdx.x, lane = tid & 63, wid = tid >> 6;
    int v = (tid < 196) ? bsum[tid] : 0;
    int x = v;
    for (int o = 1; o < 64; o <<= 1) {
        int t = __shfl_up(x, o, 64);
        if (lane >= o) x += t;
    }
    if (lane == 63) ws[wid] = x;
    __syncthreads();
    if (tid == 0) {
        int acc = 0;
        for (int w = 0; w < 4; w++) { int t = ws[w]; ws[w] = acc; acc += t; }
    }
    __syncthreads();
    if (tid < 196) boff[tid] = x + ws[wid] - v;
}

__global__ void scan3_kernel(const int* __restrict__ deg, const int* __restrict__ boff,
                             int* off) {
    __shared__ int ws[4];
    int tid = threadIdx.x, lane = tid & 63, wid = tid >> 6;
    int i = blockIdx.x * 256 + tid;
    int v = (i < NN) ? deg[i] : 0;
    int x = v;
    for (int o = 1; o < 64; o <<= 1) {
        int t = __shfl_up(x, o, 64);
        if (lane >= o) x += t;
    }
    if (lane == 63) ws[wid] = x;
    __syncthreads();
    if (tid == 0) {
        int acc = 0;
        for (int w = 0; w < 4; w++) { int t = ws[w]; ws[w] = acc; acc += t; }
    }
    __syncthreads();
    int incl = x + ws[wid] + boff[blockIdx.x];
    if (i < NN) off[i + 1] = incl;
    if (i == 0) off[0] = 0;
}

// ---------------- rank via LDS + write packed edge record (no global atomics)
__global__ __launch_bounds__(256) void scatter_kernel(const int* __restrict__ ei,
                                                      const float* __restrict__ ea,
                                                      const unsigned short* __restrict__ base_g,
                                                      const int* __restrict__ soff,
                                                      uint4* __restrict__ erec) {
    __shared__ unsigned lc[NW];
    int b = blockIdx.x, tid = threadIdx.x;
    for (int w = tid; w < NW; w += 256) lc[w] = 0;
    __syncthreads();
    int e0 = b * EPB;
    const unsigned short* brow = base_g + (size_t)b * NN;
    for (int i = tid; i < EPB; i += 256) {
        int e = e0 + i;
        int d = ei[EE + e];
        int sh = (d & 3) * 8;
        unsigned old = atomicAdd(&lc[d >> 2], 1u << sh);
        int r = (int)((old >> sh) & 0xffu);
        int pos = soff[d] + (int)brow[d] + r;
        uint4 rec;
        rec.x = (unsigned)ei[e];
        rec.y = (unsigned)e;
        rec.z = __float_as_uint(ea[e]);
        rec.w = 0;
        erec[pos] = rec;
    }
}

#define ROWFMA4(rr, av) \
    acc[rr][0] += (av) * b0; acc[rr][1] += (av) * b1; acc[rr][2] += (av) * b2; \
    acc[rr][3] += (av) * b3; acc[rr][4] += (av) * b4;

// ---------------- h = A @ W  (K = 128 or 160, A fp32 or fp16): 32 rows x 160 cols
//                  per block (1563 blocks -> ~6 blocks/CU), 4x5 register tile,
//                  simple 2-barrier staging (compiler schedules loads), att-dot
//                  epilogue reuses the As/Bs LDS (union) -> ~25 KB total LDS.
template <int K, typename AT>
__global__ __launch_bounds__(256, 6) void gemm_kernel(const AT* __restrict__ A,
                                                      const float* __restrict__ W,
                                                      const float* __restrict__ a_s,
                                                      const float* __restrict__ a_d,
                                                      __half* __restrict__ out,
                                                      float* __restrict__ al_s,
                                                      float* __restrict__ al_d) {
    __shared__ float smem[32 * ASTR + 32 * 160];   // As | Bs ; reused as hs after loop
    float* As = smem;                 // [k][row] stride ASTR=36 (float4-aligned)
    float* Bs = smem + 32 * ASTR;     // [k][c]
    float* hs = smem;                 // epilogue: [row32][h*33 + c]
    const int tid = threadIdx.x;
    const int base = blockIdx.x * 32;
    const int tc = tid & 31, tr = tid >> 5;       // col-thread, row-thread (0..7)
    const int srow = tid >> 3, skq = tid & 7;     // staging map: 32 rows x 8 chunks
    const bool rowok = (base + srow) < NN;
    const AT* arow = A + (size_t)(base + srow) * K;

    float acc[4][5];
#pragma unroll
    for (int r = 0; r < 4; r++)
#pragma unroll
        for (int c = 0; c < 5; c++) acc[r][c] = 0.f;

    for (int k0 = 0; k0 < K; k0 += 32) {
        __syncthreads();
        // ---- stage A (transposed, padded): 32 rows x 32 k
        float4 av = make_float4(0.f, 0.f, 0.f, 0.f);
        if (rowok) {
            if constexpr (sizeof(AT) == 4) {
                av = *reinterpret_cast<const float4*>(arow + k0 + skq * 4);
            } else {
                uint2 u = *reinterpret_cast<const uint2*>(arow + k0 + skq * 4);
                av = h8_to_f4(u);
            }
        }
        As[(skq * 4 + 0) * ASTR + srow] = av.x;
        As[(skq * 4 + 1) * ASTR + srow] = av.y;
        As[(skq * 4 + 2) * ASTR + srow] = av.z;
        As[(skq * 4 + 3) * ASTR + srow] = av.w;
        // ---- stage B : 32 k x 160 c  (1280 float4 / 256 threads)
#pragma unroll
        for (int i = 0; i < 5; i++) {
            int f = tid + 256 * i;
            int kk = f / 40, c4 = f - kk * 40;
            *reinterpret_cast<float4*>(&Bs[kk * 160 + c4 * 4]) =
                *reinterpret_cast<const float4*>(&W[(size_t)(k0 + kk) * HC + c4 * 4]);
        }
        __syncthreads();
#pragma unroll 8
        for (int k = 0; k < 32; k++) {
            const float4 a = *reinterpret_cast<const float4*>(&As[k * ASTR + tr * 4]);
            const float b0 = Bs[k * 160 + tc];
            const float b1 = Bs[k * 160 + tc + 32];
            const float b2 = Bs[k * 160 + tc + 64];
            const float b3 = Bs[k * 160 + tc + 96];
            const float b4 = Bs[k * 160 + tc + 128];
            ROWFMA4(0, a.x) ROWFMA4(1, a.y) ROWFMA4(2, a.z) ROWFMA4(3, a.w)
        }
    }
    // ---- store h (fp16) straight from registers
#pragma unroll
    for (int r = 0; r < 4; r++) {
        int grow = base + tr * 4 + r;
        if (grow < NN) {
            __half* op = out + (size_t)grow * HC + tc;
            op[0]   = __float2half(acc[r][0]);
            op[32]  = __float2half(acc[r][1]);
            op[64]  = __float2half(acc[r][2]);
            op[96]  = __float2half(acc[r][3]);
            op[128] = __float2half(acc[r][4]);
        }
    }
    // ---- att-dot epilogue (hs unions As/Bs; single pass for 32 rows)
    __syncthreads();                    // everyone done reading As/Bs
#pragma unroll
    for (int r = 0; r < 4; r++)
#pragma unroll
        for (int ci = 0; ci < 5; ci++)
            hs[(tr * 4 + r) * 168 + ci * 33 + tc] = acc[r][ci];
    __syncthreads();
    for (int t = tid; t < 320; t += 256) {
        int row32 = t / 10;
        int rem = t - row32 * 10;
        int h = rem >> 1, sd = rem & 1;
        int grow = base + row32;
        if (grow < NN) {
            const float* av = (sd ? a_d : a_s) + h * 32;
            const float* hp = &hs[row32 * 168 + h * 33];
            float s = 0.f;
#pragma unroll
            for (int c = 0; c < 32; c++) s += hp[c] * av[c];
            s *= LOG2E;                       // exp2-domain logits
            if (sd) al_d[(size_t)grow * NH + h] = s;
            else    al_s[(size_t)grow * ALS8 + h] = s;
        }
    }
}

// ------------- per-node (one WAVE per node, 4 nodes per block): segment softmax
//               (exp2-domain) + weighted fp16 gather + bias/lrelu/LN -> fp16 x_out.
//               Exactly ONE __syncthreads on both paths.
__global__ __launch_bounds__(256, 8) void aggregate_kernel(
    const int* __restrict__ soff, const uint4* __restrict__ erec,
    const __half* __restrict__ hfeat, const float* __restrict__ als,
    const float* __restrict__ al_d, const float* __restrict__ s_e,
    const float* __restrict__ bias, const float* __restrict__ g_ln,
    const float* __restrict__ b_ln,
    float* __restrict__ alpha_out, __half* __restrict__ x_out) {
    const int wave = threadIdx.x >> 6;
    const int lane = threadIdx.x & 63;
    const int n = blockIdx.x * 4 + wave;
    __shared__ float w_sh_all[4][CH * NH];
    __shared__ int ioff_all[4][CH];      // byte offsets into hfeat (src*HC*2)
    float* w_sh = w_sh_all[wave];
    int* ioff_sh = ioff_all[wave];

    const int s0 = soff[n];
    const int deg = soff[n + 1] - s0;
    const int items = deg + 1;

    float adr[NH], ser[NH];
#pragma unroll
    for (int h = 0; h < NH; h++) { adr[h] = al_d[n * NH + h]; ser[h] = s_e[h]; }

    const int c0 = 4 * lane;      // lanes 0..39 own channels c0..c0+3
    const int hd = lane >> 3;     // head for those channels (valid for lane<40)
    float4 acc = make_float4(0.f, 0.f, 0.f, 0.f);

    if (items <= CH) {
        // ---- pass A: logits into registers (2 tiles x 5 heads), per-head max, ea sum
        float rw[2][NH];
        float lm[NH];
#pragma unroll
        for (int h = 0; h < NH; h++) lm[h] = -3.0e38f;
        float eas = 0.f;
        int myy[2];
#pragma unroll
        for (int t = 0; t < 2; t++) {
            int i = lane + 64 * t;
            if (i < deg) {
                uint4 rec = erec[s0 + i];
                int src = (int)rec.x;
                float eav = __uint_as_float(rec.z);
                ioff_sh[i] = src * (HC * 2);
                myy[t] = (int)rec.y;
                eas += eav;
                const float* ap = als + (size_t)src * ALS8;
                float4 a4 = *reinterpret_cast<const float4*>(ap);
                float a5 = ap[4];
                float asv[5] = {a4.x, a4.y, a4.z, a4.w, a5};
#pragma unroll
                for (int h = 0; h < NH; h++) {
                    float r = lrelu(asv[h] + adr[h] + eav * ser[h], 0.2f);
                    rw[t][h] = r;
                    lm[h] = fmaxf(lm[h], r);
                }
            }
        }
#pragma unroll
        for (int o = 1; o < 64; o <<= 1) {
#pragma unroll
            for (int h = 0; h < NH; h++) lm[h] = fmaxf(lm[h], __shfl_xor(lm[h], o, 64));
            eas += __shfl_xor(eas, o, 64);
        }
        float emean = eas / fmaxf((float)deg, 1.f);
        float m[NH], rs[NH];
        {
            const float* ap = als + (size_t)n * ALS8;
            float4 a4 = *reinterpret_cast<const float4*>(ap);
            float a5 = ap[4];
            float asv[5] = {a4.x, a4.y, a4.z, a4.w, a5};
#pragma unroll
            for (int h = 0; h < NH; h++) {
                rs[h] = lrelu(asv[h] + adr[h] + emean * ser[h], 0.2f);
                m[h] = fmaxf(lm[h], rs[h]);
            }
        }
        // ---- pass B: exp2 in registers + sum
        float ls[NH] = {0.f, 0.f, 0.f, 0.f, 0.f};
#pragma unroll
        for (int t = 0; t < 2; t++) {
            int i = lane + 64 * t;
            if (i < deg) {
#pragma unroll
                for (int h = 0; h < NH; h++) {
                    float w = exp2f(rw[t][h] - m[h]);
                    rw[t][h] = w;
                    ls[h] += w;
                }
            } else if (i == deg) {          // self-loop owner lane
                ioff_sh[i] = n * (HC * 2);
#pragma unroll
                for (int h = 0; h < NH; h++) {
                    float w = exp2f(rs[h] - m[h]);
                    rw[t][h] = w;
                    ls[h] += w;
                }
            }
        }
#pragma unroll
        for (int o = 1; o < 64; o <<= 1) {
#pragma unroll
            for (int h = 0; h < NH; h++) ls[h] += __shfl_xor(ls[h], o, 64);
        }
        float dinv[NH];
#pragma unroll
        for (int h = 0; h < NH; h++) dinv[h] = 1.f / ls[h];
        // ---- normalize: final weights -> LDS + alpha writeback
#pragma unroll
        for (int t = 0; t < 2; t++) {
            int i = lane + 64 * t;
            if (i < items) {
                int opos = (i < deg) ? myy[t] : (EE + n);
#pragma unroll
                for (int h = 0; h < NH; h++) {
                    float w = rw[t][h] * dinv[h];
                    w_sh[i * NH + h] = w;
                    alpha_out[(size_t)opos * NH + h] = w;
                }
            }
        }
        __syncthreads();                                   // [barrier #1 of 1]
        // ---- pass C: 4-deep pipelined fp16 gather via precomputed byte offsets
        if (lane < 40) {
            const char* hb = (const char*)hfeat + (size_t)(c0 * 2);
            for (int i0 = 0; i0 < items; i0 += 4) {
                float wv[4];
                uint2 hv[4];
#pragma unroll
                for (int j = 0; j < 4; j++) {
                    int i = i0 + j;
                    bool ok = i < items;
                    int ii = ok ? i : 0;
                    wv[j] = ok ? w_sh[ii * NH + hd] : 0.f;
                    hv[j] = *reinterpret_cast<const uint2*>(hb + (size_t)(unsigned)ioff_sh[ii]);
                }
#pragma unroll
                for (int j = 0; j < 4; j++) {
                    __half2 p0 = *reinterpret_cast<__half2*>(&hv[j].x);
                    __half2 p1 = *reinterpret_cast<__half2*>(&hv[j].y);
                    acc.x += wv[j] * __low2float(p0);
                    acc.y += wv[j] * __high2float(p0);
                    acc.z += wv[j] * __low2float(p1);
                    acc.w += wv[j] * __high2float(p1);
                }
            }
        }
    } else {
        // ---- slow path (deg >= CH): streaming recompute, no LDS
        float lm[NH];
#pragma unroll
        for (int h = 0; h < NH; h++) lm[h] = -3.0e38f;
        float eas = 0.f;
        for (int i = lane; i < deg; i += 64) {
            uint4 rec = erec[s0 + i];
            int src = (int)rec.x;
            float eav = __uint_as_float(rec.z);
            eas += eav;
            const float* ap = als + (size_t)src * ALS8;
            float4 a4 = *reinterpret_cast<const float4*>(ap);
            float a5 = ap[4];
            float asv[5] = {a4.x, a4.y, a4.z, a4.w, a5};
#pragma unroll
            for (int h = 0; h < NH; h++) {
                float r = lrelu(asv[h] + adr[h] + eav * ser[h], 0.2f);
                lm[h] = fmaxf(lm[h], r);
            }
        }
#pragma unroll
        for (int o = 1; o < 64; o <<= 1) {
#pragma unroll
            for (int h = 0; h < NH; h++) lm[h] = fmaxf(lm[h], __shfl_xor(lm[h], o, 64));
            eas += __shfl_xor(eas, o, 64);
        }
        float emean = eas / fmaxf((float)deg, 1.f);
        float m[NH], rs[NH];
        {
            const float* ap = als + (size_t)n * ALS8;
#pragma unroll
            for (int h = 0; h < NH; h++) {
                rs[h] = lrelu(ap[h] + adr[h] + emean * ser[h], 0.2f);
                m[h] = fmaxf(lm[h], rs[h]);
            }
        }
        float ls[NH] = {0.f, 0.f, 0.f, 0.f, 0.f};
        for (int i = lane; i < items; i += 64) {
            int src; float eav;
            if (i < deg) { uint4 rec = erec[s0 + i]; src = (int)rec.x; eav = __uint_as_float(rec.z); }
            else         { src = n; eav = emean; }
            const float* ap = als + (size_t)src * ALS8;
#pragma unroll
            for (int h = 0; h < NH; h++) {
                float r = lrelu(ap[h] + adr[h] + eav * ser[h], 0.2f);
                ls[h] += exp2f(r - m[h]);
            }
        }
#pragma unroll
        for (int o = 1; o < 64; o <<= 1) {
#pragma unroll
            for (int h = 0; h < NH; h++) ls[h] += __shfl_xor(ls[h], o, 64);
        }
        float dinv[NH];
#pragma unroll
        for (int h = 0; h < NH; h++) dinv[h] = 1.f / ls[h];
        __syncthreads();                                   // [barrier #1 of 1]
        for (int i = lane; i < items; i += 64) {
            int src; float eav; int opos;
            if (i < deg) { uint4 rec = erec[s0 + i]; src = (int)rec.x; eav = __uint_as_float(rec.z); opos = (int)rec.y; }
            else         { src = n; eav = emean; opos = EE + n; }
            const float* ap = als + (size_t)src * ALS8;
#pragma unroll
            for (int h = 0; h < NH; h++) {
                float r = lrelu(ap[h] + adr[h] + eav * ser[h], 0.2f);
                alpha_out[(size_t)opos * NH + h] = exp2f(r - m[h]) * dinv[h];
            }
        }
        if (lane < 40) {
            for (int i = 0; i < items; i++) {
                int src; float eav;
                if (i < deg) { uint4 rec = erec[s0 + i]; src = (int)rec.x; eav = __uint_as_float(rec.z); }
                else         { src = n; eav = emean; }
                float r = lrelu(als[(size_t)src * ALS8 + hd] + adr[hd] + eav * ser[hd], 0.2f);
                float w = exp2f(r - m[hd]) * dinv[hd];
                uint2 hv = *reinterpret_cast<const uint2*>(
                    &hfeat[(size_t)src * HC + c0]);
                float4 hf = h8_to_f4(hv);
                acc.x += w * hf.x; acc.y += w * hf.y;
                acc.z += w * hf.z; acc.w += w * hf.w;
            }
        }
    }

    // ---- bias + lrelu + fused LayerNorm across 160 channels (wave butterfly)
    float4 v = make_float4(0.f, 0.f, 0.f, 0.f);
    float p1 = 0.f, p2 = 0.f;
    if (lane < 40) {
        const float4 b4 = *reinterpret_cast<const float4*>(&bias[c0]);
        v.x = lrelu(acc.x + b4.x, 0.01f);
        v.y = lrelu(acc.y + b4.y, 0.01f);
        v.z = lrelu(acc.z + b4.z, 0.01f);
        v.w = lrelu(acc.w + b4.w, 0.01f);
        p1 = v.x + v.y + v.z + v.w;
        p2 = v.x * v.x + v.y * v.y + v.z * v.z + v.w * v.w;
    }
#pragma unroll
    for (int o = 1; o < 64; o <<= 1) {
        p1 += __shfl_xor(p1, o, 64);
        p2 += __shfl_xor(p2, o, 64);
    }
    float mean = p1 * (1.f / (float)HC);
    float var = p2 * (1.f / (float)HC) - mean * mean;
    float rstd = rsqrtf(var + 1e-5f);
    if (lane < 40) {
        const float4 g4 = *reinterpret_cast<const float4*>(&g_ln[c0]);
        const float4 bb = *reinterpret_cast<const float4*>(&b_ln[c0]);
        float ox = (v.x - mean) * rstd * g4.x + bb.x;
        float oy = (v.y - mean) * rstd * g4.y + bb.y;
        float oz = (v.z - mean) * rstd * g4.z + bb.z;
        float ow = (v.w - mean) * rstd * g4.w + bb.w;
        __half2 h01 = __floats2half2_rn(ox, oy);
        __half2 h23 = __floats2half2_rn(oz, ow);
        uint2 st;
        st.x = *reinterpret_cast<unsigned*>(&h01);
        st.y = *reinterpret_cast<unsigned*>(&h23);
        *reinterpret_cast<uint2*>(&x_out[(size_t)n * HC + c0]) = st;
    }
}

// -------- x3 = lrelu(x2 @ mw + mb) (x2 fp16); 32-row tiles; fused pooled sums
__global__ __launch_bounds__(256, 6) void gemm3_kernel(const __half* __restrict__ A,
                                                       const float* __restrict__ W,
                                                       const float* __restrict__ bias,
                                                       const int* __restrict__ batch,
                                                       float* __restrict__ x3,
                                                       float* __restrict__ psum) {
    __shared__ float smem[32 * ASTR + 32 * 160];
    float* As = smem;
    float* Bs = smem + 32 * ASTR;
    __shared__ int bt[32];
    const int tid = threadIdx.x;
    const int base = blockIdx.x * 32;
    const int tc = tid & 31, tr = tid >> 5;
    const int srow = tid >> 3, skq = tid & 7;
    const bool rowok = (base + srow) < NN;
    const __half* arow = A + (size_t)(base + srow) * HC;

    if (tid < 32) bt[tid] = batch[(base + tid < NN) ? (base + tid) : (NN - 1)];

    float acc[4][5];
#pragma unroll
    for (int r = 0; r < 4; r++)
#pragma unroll
        for (int c = 0; c < 5; c++) acc[r][c] = 0.f;

    for (int k0 = 0; k0 < HC; k0 += 32) {
        __syncthreads();
        float4 av = make_float4(0.f, 0.f, 0.f, 0.f);
        if (rowok) {
            uint2 u = *reinterpret_cast<const uint2*>(arow + k0 + skq * 4);
            av = h8_to_f4(u);
        }
        As[(skq * 4 + 0) * ASTR + srow] = av.x;
        As[(skq * 4 + 1) * ASTR + srow] = av.y;
        As[(skq * 4 + 2) * ASTR + srow] = av.z;
        As[(skq * 4 + 3) * ASTR + srow] = av.w;
#pragma unroll
        for (int i = 0; i < 5; i++) {
            int f = tid + 256 * i;
            int kk = f / 40, c4 = f - kk * 40;
            *reinterpret_cast<float4*>(&Bs[kk * 160 + c4 * 4]) =
                *reinterpret_cast<const float4*>(&W[(size_t)(k0 + kk) * HC + c4 * 4]);
        }
        __syncthreads();
#pragma unroll 8
        for (int k = 0; k < 32; k++) {
            const float4 a = *reinterpret_cast<const float4*>(&As[k * ASTR + tr * 4]);
            const float b0 = Bs[k * 160 + tc];
            const float b1 = Bs[k * 160 + tc + 32];
            const float b2 = Bs[k * 160 + tc + 64];
            const float b3 = Bs[k * 160 + tc + 96];
            const float b4 = Bs[k * 160 + tc + 128];
            ROWFMA4(0, a.x) ROWFMA4(1, a.y) ROWFMA4(2, a.z) ROWFMA4(3, a.w)
        }
    }
    float bj[5];
#pragma unroll
    for (int ci = 0; ci < 5; ci++) bj[ci] = bias[tc + 32 * ci];
    float run[5] = {0.f, 0.f, 0.f, 0.f, 0.f};
    int g = bt[tr * 4];
#pragma unroll
    for (int r = 0; r < 4; r++) {
        int grow = base + tr * 4 + r;
        bool ok = grow < NN;
        float vv[5];
#pragma unroll
        for (int ci = 0; ci < 5; ci++) vv[ci] = lrelu(acc[r][ci] + bj[ci], 0.01f);
        if (ok) {
            float* op = x3 + (size_t)grow * HC + tc;
            op[0] = vv[0]; op[32] = vv[1]; op[64] = vv[2]; op[96] = vv[3]; op[128] = vv[4];
        }
        int gb = bt[tr * 4 + r];
        if (gb != g) {
#pragma unroll
            for (int ci = 0; ci < 5; ci++) {
                atomicAdd(&psum[g * HC + tc + 32 * ci], run[ci]);
                run[ci] = 0.f;
            }
            g = gb;
        }
        if (ok) {
#pragma unroll
            for (int ci = 0; ci < 5; ci++) run[ci] += vv[ci];
        }
    }
#pragma unroll
    for (int ci = 0; ci < 5; ci++) atomicAdd(&psum[g * HC + tc + 32 * ci], run[ci]);
}

__global__ void pooldiv_kernel(const float* __restrict__ psum, const int* __restrict__ gcnt,
                               float* pooled_out) {
    int i = blockIdx.x * 256 + threadIdx.x;
    if (i < NG * HC) pooled_out[i] = psum[i] / fmaxf((float)gcnt[i / HC], 1.f);
}

// ---------------------------------------------------------------------- launch
extern "C" void kernel_launch(void* const* d_in, const int* in_sizes, int n_in,
                              void* d_out, int out_size, void* d_ws, size_t ws_size,
                              hipStream_t stream) {
    const float* x    = (const float*)d_in[0];
    const int*   ei   = (const int*)d_in[1];
    const float* ea   = (const float*)d_in[2];
    const int*   batch= (const int*)d_in[3];
    const float* w1   = (const float*)d_in[4];
    const float* we1  = (const float*)d_in[5];
    const float* as1  = (const float*)d_in[6];
    const float* ad1  = (const float*)d_in[7];
    const float* ae1  = (const float*)d_in[8];
    const float* b1   = (const float*)d_in[9];
    const float* w2   = (const float*)d_in[10];
    const float* we2  = (const float*)d_in[11];
    const float* as2  = (const float*)d_in[12];
    const float* ad2  = (const float*)d_in[13];
    const float* ae2  = (const float*)d_in[14];
    const float* b2   = (const float*)d_in[15];
    const float* ln1g = (const float*)d_in[16];
    const float* ln1b = (const float*)d_in[17];
    const float* ln2g = (const float*)d_in[18];
    const float* ln2b = (const float*)d_in[19];
    const float* mw   = (const float*)d_in[20];
    const float* mb   = (const float*)d_in[21];

    float* out = (float*)d_out;
    float* pooled_out = out + (size_t)NN * HC;
    float* a1 = pooled_out + NG * HC;
    float* a2 = a1 + (size_t)(EE + NN) * NH;

    char* wp = (char*)d_ws;
    auto alloc = [&](size_t bytes) {
        void* p = (void*)wp;
        wp += (bytes + 255) & ~(size_t)255;
        return p;
    };
    // 32MB region, triple-overlaid in time:
    //   [0..8)   hist_g   (dead after sscan)     -> [0..16)  h fp16
    //   [8..24)  base_g   (dead after scatter)   -> [16..32) x12h fp16
    char* region = (char*)alloc(32 * 1024 * 1024);
    __half* hbuf = (__half*)region;                               // 16 MB fp16 h
    __half* x12h = (__half*)(region + 16 * 1024 * 1024);          // 16 MB fp16 x1/x2
    unsigned*       hist_g = (unsigned*)region;                   // 8 MB
    unsigned short* base_g = (unsigned short*)(region + 8 * 1024 * 1024); // 16 MB
    uint4* erec  = (uint4*)alloc((size_t)EE * 16);       // 12.8 MB
    float* als   = (float*)alloc((size_t)NN * ALS8 * 4); // padded al_s
    float* ald   = (float*)alloc((size_t)NN * NH * 4);
    int*   deg   = (int*)alloc((size_t)NN * 4);
    int*   soff  = (int*)alloc((size_t)(NN + 1) * 4);
    float* sbuf  = (float*)alloc(64);
    float* psum  = (float*)alloc((size_t)NG * HC * 4);
    int*   gcnt  = (int*)alloc((size_t)NG * 4);
    int*   bsum  = (int*)alloc(256 * 4);
    int*   boff  = (int*)alloc(256 * 4);

    prep_kernel<<<40, 256, 0, stream>>>(batch, psum, gcnt, we1, ae1, we2, ae2, sbuf);
    hist_kernel<<<NB, 256, 0, stream>>>(ei, hist_g);
    sscan_kernel<<<49, 256, 0, stream>>>(hist_g, base_g, deg);
    scan1_kernel<<<196, 256, 0, stream>>>(deg, bsum);
    scan2_kernel<<<1, 256, 0, stream>>>(bsum, boff);
    scan3_kernel<<<196, 256, 0, stream>>>(deg, boff, soff);
    scatter_kernel<<<NB, 256, 0, stream>>>(ei, ea, base_g, soff, erec);

    gemm_kernel<128, float><<<1563, 256, 0, stream>>>(x, w1, as1, ad1, hbuf, als, ald);
    aggregate_kernel<<<12500, 256, 0, stream>>>(soff, erec, hbuf, als, ald,
                                                sbuf, b1, ln1g, ln1b, a1, x12h);

    gemm_kernel<160, __half><<<1563, 256, 0, stream>>>(x12h, w2, as2, ad2, hbuf, als, ald);
    aggregate_kernel<<<12500, 256, 0, stream>>>(soff, erec, hbuf, als, ald,
                                                sbuf + 5, b2, ln2g, ln2b, a2, x12h);

    gemm3_kernel<<<1563, 256, 0, stream>>>(x12h, mw, mb, batch, out, psum);
    pooldiv_kernel<<<40, 256, 0, stream>>>(psum, gcnt, pooled_out);
}

// Round 6
// 493.387 us; speedup vs baseline: 1.1285x; 1.0649x over previous
//
#include <hip/hip_runtime.h>
#include <hip/hip_fp16.h>
#include <math.h>

#define NN 50000
#define EE 800000
#define FIN 128
#define NH 5
#define HC 160
#define NG 64
#define CH 128        // fast-path max items per node (deg <= 127)
#define NB 160        // sort blocks
#define EPB 5000      // edges per sort block (NB*EPB == EE)
#define NW 12500      // packed histogram words (4 byte-bins per word)
#define ALS8 8        // padded stride for al_s (float4 + float loads)
#define LOG2E 1.4426950408889634f
#define RB 48         // rows per GEMM block
#define ASTR2 52      // As padded k-stride (multiple of 4 for aligned float4 reads)

__device__ __forceinline__ float lrelu(float x, float s) { return x >= 0.f ? x : s * x; }

// unpack 4 consecutive fp16 (8B) to float4
__device__ __forceinline__ float4 h8_to_f4(uint2 u) {
    __half2 a = *reinterpret_cast<__half2*>(&u.x);
    __half2 b = *reinterpret_cast<__half2*>(&u.y);
    float2 fa = __half22float2(a), fb = __half22float2(b);
    return make_float4(fa.x, fa.y, fb.x, fb.y);
}

// ---------------- psum zero + per-graph node counts + per-layer s[h] (merged preps)
__global__ void prep_kernel(const int* __restrict__ batch, float* psum, int* gcnt,
                            const float* we1, const float* ae1,
                            const float* we2, const float* ae2, float* s_out) {
    int i = blockIdx.x * 256 + threadIdx.x;
    if (i < NG * HC) psum[i] = 0.f;
    if (i < NG) {
        int lo = 0, hi = NN;
        while (lo < hi) { int m = (lo + hi) >> 1; if (batch[m] < i) lo = m + 1; else hi = m; }
        int s = lo;
        lo = 0; hi = NN;
        int g1 = i + 1;
        while (lo < hi) { int m = (lo + hi) >> 1; if (batch[m] < g1) lo = m + 1; else hi = m; }
        gcnt[i] = lo - s;
    }
    if (i < 10) {
        const float* we = (i < 5) ? we1 : we2;
        const float* ae = (i < 5) ? ae1 : ae2;
        int h = i % 5;
        float s = 0.f;
        for (int c = 0; c < 32; c++) s += we[h * 32 + c] * ae[h * 32 + c];
        s_out[i] = s * LOG2E;          // exp2-domain
    }
}

// ---------------- per-block LDS histogram of dst (byte-packed, no global atomics)
__global__ __launch_bounds__(256) void hist_kernel(const int* __restrict__ ei,
                                                   unsigned* __restrict__ hist_g) {
    __shared__ unsigned lh[NW];
    int b = blockIdx.x, tid = threadIdx.x;
    for (int w = tid; w < NW; w += 256) lh[w] = 0;
    __syncthreads();
    const int* dstp = ei + EE + b * EPB;
    for (int i = tid; i < EPB; i += 256) {
        int d = dstp[i];
        atomicAdd(&lh[d >> 2], 1u << ((d & 3) * 8));
    }
    __syncthreads();
    unsigned* outp = hist_g + (size_t)b * NW;
    for (int w = tid; w < NW; w += 256) outp[w] = lh[w];
}

// ---------------- column scan over blocks: per-(block,bin) base + total deg
__global__ void sscan_kernel(const unsigned* __restrict__ hist_g,
                             unsigned short* __restrict__ base_g, int* __restrict__ deg) {
    int w = blockIdx.x * 256 + threadIdx.x;
    if (w >= NW) return;
    unsigned r0 = 0, r1 = 0, r2 = 0, r3 = 0;
    for (int b = 0; b < NB; b++) {
        unsigned x = hist_g[(size_t)b * NW + w];
        uint2 st;
        st.x = r0 | (r1 << 16);
        st.y = r2 | (r3 << 16);
        *reinterpret_cast<uint2*>(&base_g[(size_t)b * NN + 4 * w]) = st;
        r0 += x & 0xffu; r1 += (x >> 8) & 0xffu; r2 += (x >> 16) & 0xffu; r3 += (x >> 24) & 0xffu;
    }
    uint4 dv; dv.x = r0; dv.y = r1; dv.z = r2; dv.w = r3;
    *reinterpret_cast<uint4*>(&deg[4 * w]) = dv;
}

// ------------------------------------------------------- 3-phase parallel scan
__global__ void scan1_kernel(const int* __restrict__ deg, int* bsum) {
    __shared__ int ws[4];
    int tid = threadIdx.x, lane = tid & 63, wid = tid >> 6;
    int i = blockIdx.x * 256 + tid;
    int v = (i < NN) ? deg[i] : 0;
    for (int o = 32; o >= 1; o >>= 1) v += __shfl_down(v, o, 64);
    if (lane == 0) ws[wid] = v;
    __syncthreads();
    if (tid == 0) bsum[blockIdx.x] = ws[0] + ws[1] + ws[2] + ws[3];
}

__global__ void scan2_kernel(int* bsum, int* boff) {
    __shared__ int ws[4];
    int tid = threadIdx.x, lane = tid & 63, wid = tid >> 6;
    int v = (tid < 196) ? bsum[tid] : 0;
    int x = v;
    for (int o = 1; o < 64; o <<= 1) {
        int t = __shfl_up(x, o, 64);
        if (lane >= o) x += t;
    }
    if (lane == 63) ws[wid] = x;
    __syncthreads();
    if (tid == 0) {
        int acc = 0;
        for (int w = 0; w < 4; w++) { int t = ws[w]; ws[w] = acc; acc += t; }
    }
    __syncthreads();
    if (tid < 196) boff[tid] = x + ws[wid] - v;
}

__global__ void scan3_kernel(const int* __restrict__ deg, const int* __restrict__ boff,
                             int* off) {
    __shared__ int ws[4];
    int tid = threadIdx.x, lane = tid & 63, wid = tid >> 6;
    int i = blockIdx.x * 256 + tid;
    int v = (i < NN) ? deg[i] : 0;
    int x = v;
    for (int o = 1; o < 64; o <<= 1) {
        int t = __shfl_up(x, o, 64);
        if (lane >= o) x += t;
    }
    if (lane == 63) ws[wid] = x;
    __syncthreads();
    if (tid == 0) {
        int acc = 0;
        for (int w = 0; w < 4; w++) { int t = ws[w]; ws[w] = acc; acc += t; }
    }
    __syncthreads();
    int incl = x + ws[wid] + boff[blockIdx.x];
    if (i < NN) off[i + 1] = incl;
    if (i == 0) off[0] = 0;
}

// ---------------- rank via LDS + write packed edge record (no global atomics)
__global__ __launch_bounds__(256) void scatter_kernel(const int* __restrict__ ei,
                                                      const float* __restrict__ ea,
                                                      const unsigned short* __restrict__ base_g,
                                                      const int* __restrict__ soff,
                                                      uint4* __restrict__ erec) {
    __shared__ unsigned lc[NW];
    int b = blockIdx.x, tid = threadIdx.x;
    for (int w = tid; w < NW; w += 256) lc[w] = 0;
    __syncthreads();
    int e0 = b * EPB;
    const unsigned short* brow = base_g + (size_t)b * NN;
    for (int i = tid; i < EPB; i += 256) {
        int e = e0 + i;
        int d = ei[EE + e];
        int sh = (d & 3) * 8;
        unsigned old = atomicAdd(&lc[d >> 2], 1u << sh);
        int r = (int)((old >> sh) & 0xffu);
        int pos = soff[d] + (int)brow[d] + r;
        uint4 rec;
        rec.x = (unsigned)ei[e];
        rec.y = (unsigned)e;
        rec.z = __float_as_uint(ea[e]);
        rec.w = 0;
        erec[pos] = rec;
    }
}

// ---------------- h = A @ W  (K = 128 or 160, A fp32 or fp16): 48 rows x 160 cols
//   per block; 240 active threads = 6 row-groups x 40 col-groups; per-thread tile
//   8 rows x 4 CONSECUTIVE cols -> inner loop is 3x ds_read_b128 per 32 FMAs
//   (FMA-bound, was LDS-BW-bound).  Att-dots via in-register 8-lane shfl_xor
//   reduction (each head's 32 cols = 8 consecutive lanes) -- no LDS epilogue.
template <int K, typename AT>
__global__ __launch_bounds__(256, 5) void gemm_kernel(const AT* __restrict__ A,
                                                      const float* __restrict__ W,
                                                      const float* __restrict__ a_s,
                                                      const float* __restrict__ a_d,
                                                      __half* __restrict__ out,
                                                      float* __restrict__ al_s,
                                                      float* __restrict__ al_d) {
    __shared__ float As[32 * ASTR2];   // [k][row]  (6.5 KB)
    __shared__ float Bs[32 * 160];     // [k][c]    (20 KB)
    const int tid = threadIdx.x;
    const int base = blockIdx.x * RB;
    const int cg = tid % 40;           // col group: cols cg*4 .. cg*4+3
    const int rg = tid / 40;           // row group 0..5 (tid>=240 inactive)
    const bool active = tid < 240;
    const int hd = cg >> 3;            // head of my 4 cols

    float as4[4], ad4[4];
#pragma unroll
    for (int j = 0; j < 4; j++) {      // a_s flat layout [h*32+c] == col index
        as4[j] = a_s[cg * 4 + j];
        ad4[j] = a_d[cg * 4 + j];
    }

    float acc[8][4];
#pragma unroll
    for (int r = 0; r < 8; r++)
#pragma unroll
        for (int j = 0; j < 4; j++) acc[r][j] = 0.f;

    for (int k0 = 0; k0 < K; k0 += 32) {
        __syncthreads();
        // ---- stage A (transposed, padded): 48 rows x 32 k  (384 4-k chunks)
        for (int f = tid; f < 384; f += 256) {
            int srow = f >> 3, skq = f & 7;
            float4 av = make_float4(0.f, 0.f, 0.f, 0.f);
            if (base + srow < NN) {
                const AT* ap = A + (size_t)(base + srow) * K + k0 + skq * 4;
                if constexpr (sizeof(AT) == 4) {
                    av = *reinterpret_cast<const float4*>(ap);
                } else {
                    av = h8_to_f4(*reinterpret_cast<const uint2*>(ap));
                }
            }
            As[(skq * 4 + 0) * ASTR2 + srow] = av.x;
            As[(skq * 4 + 1) * ASTR2 + srow] = av.y;
            As[(skq * 4 + 2) * ASTR2 + srow] = av.z;
            As[(skq * 4 + 3) * ASTR2 + srow] = av.w;
        }
        // ---- stage B : 32 k x 160 c  (1280 float4 / 256 threads)
#pragma unroll
        for (int i = 0; i < 5; i++) {
            int f = tid + 256 * i;
            int kk = f / 40, c4 = f - kk * 40;
            *reinterpret_cast<float4*>(&Bs[kk * 160 + c4 * 4]) =
                *reinterpret_cast<const float4*>(&W[(size_t)(k0 + kk) * HC + c4 * 4]);
        }
        __syncthreads();
        if (active) {
#pragma unroll 8
            for (int k = 0; k < 32; k++) {
                const float4 b = *reinterpret_cast<const float4*>(&Bs[k * 160 + cg * 4]);
                const float4 a0 = *reinterpret_cast<const float4*>(&As[k * ASTR2 + rg * 8]);
                const float4 a1 = *reinterpret_cast<const float4*>(&As[k * ASTR2 + rg * 8 + 4]);
#define FMA4(rr, av) acc[rr][0] += (av) * b.x; acc[rr][1] += (av) * b.y; \
                     acc[rr][2] += (av) * b.z; acc[rr][3] += (av) * b.w;
                FMA4(0, a0.x) FMA4(1, a0.y) FMA4(2, a0.z) FMA4(3, a0.w)
                FMA4(4, a1.x) FMA4(5, a1.y) FMA4(6, a1.z) FMA4(7, a1.w)
#undef FMA4
            }
        }
    }
    // ---- store h (fp16, 8B per row) + att-dot partials
    float ps[8], pd[8];
    if (active) {
#pragma unroll
        for (int r = 0; r < 8; r++) {
            int grow = base + rg * 8 + r;
            if (grow < NN) {
                __half2 h01 = __floats2half2_rn(acc[r][0], acc[r][1]);
                __half2 h23 = __floats2half2_rn(acc[r][2], acc[r][3]);
                uint2 st;
                st.x = *reinterpret_cast<unsigned*>(&h01);
                st.y = *reinterpret_cast<unsigned*>(&h23);
                *reinterpret_cast<uint2*>(&out[(size_t)grow * HC + cg * 4]) = st;
            }
            ps[r] = acc[r][0] * as4[0] + acc[r][1] * as4[1] +
                    acc[r][2] * as4[2] + acc[r][3] * as4[3];
            pd[r] = acc[r][0] * ad4[0] + acc[r][1] * ad4[1] +
                    acc[r][2] * ad4[2] + acc[r][3] * ad4[3];
        }
    } else {
#pragma unroll
        for (int r = 0; r < 8; r++) { ps[r] = 0.f; pd[r] = 0.f; }
    }
    // ---- 8-lane butterfly (cols 0..31 of head hd live in 8 consecutive lanes)
#pragma unroll
    for (int o = 1; o < 8; o <<= 1) {
#pragma unroll
        for (int r = 0; r < 8; r++) {
            ps[r] += __shfl_xor(ps[r], o, 64);
            pd[r] += __shfl_xor(pd[r], o, 64);
        }
    }
    if (active && (cg & 7) == 0) {
#pragma unroll
        for (int r = 0; r < 8; r++) {
            int grow = base + rg * 8 + r;
            if (grow < NN) {
                al_s[(size_t)grow * ALS8 + hd] = ps[r] * LOG2E;
                al_d[(size_t)grow * NH + hd] = pd[r] * LOG2E;
            }
        }
    }
}

// ------------- per-node (one WAVE per node, 4 nodes per block): segment softmax
//               (exp2-domain) + weighted fp16 gather + bias/lrelu/LN -> fp16 x_out.
//               Exactly ONE __syncthreads on both paths.
__global__ __launch_bounds__(256, 8) void aggregate_kernel(
    const int* __restrict__ soff, const uint4* __restrict__ erec,
    const __half* __restrict__ hfeat, const float* __restrict__ als,
    const float* __restrict__ al_d, const float* __restrict__ s_e,
    const float* __restrict__ bias, const float* __restrict__ g_ln,
    const float* __restrict__ b_ln,
    float* __restrict__ alpha_out, __half* __restrict__ x_out) {
    const int wave = threadIdx.x >> 6;
    const int lane = threadIdx.x & 63;
    const int n = blockIdx.x * 4 + wave;
    __shared__ float w_sh_all[4][CH * NH];
    __shared__ int ioff_all[4][CH];      // byte offsets into hfeat (src*HC*2)
    float* w_sh = w_sh_all[wave];
    int* ioff_sh = ioff_all[wave];

    const int s0 = soff[n];
    const int deg = soff[n + 1] - s0;
    const int items = deg + 1;

    float adr[NH], ser[NH];
#pragma unroll
    for (int h = 0; h < NH; h++) { adr[h] = al_d[n * NH + h]; ser[h] = s_e[h]; }

    const int c0 = 4 * lane;      // lanes 0..39 own channels c0..c0+3
    const int hd = lane >> 3;     // head for those channels (valid for lane<40)
    float4 acc = make_float4(0.f, 0.f, 0.f, 0.f);

    if (items <= CH) {
        // ---- pass A: logits into registers (2 tiles x 5 heads), per-head max, ea sum
        float rw[2][NH];
        float lm[NH];
#pragma unroll
        for (int h = 0; h < NH; h++) lm[h] = -3.0e38f;
        float eas = 0.f;
        int myy[2];
#pragma unroll
        for (int t = 0; t < 2; t++) {
            int i = lane + 64 * t;
            if (i < deg) {
                uint4 rec = erec[s0 + i];
                int src = (int)rec.x;
                float eav = __uint_as_float(rec.z);
                ioff_sh[i] = src * (HC * 2);
                myy[t] = (int)rec.y;
                eas += eav;
                const float* ap = als + (size_t)src * ALS8;
                float4 a4 = *reinterpret_cast<const float4*>(ap);
                float a5 = ap[4];
                float asv[5] = {a4.x, a4.y, a4.z, a4.w, a5};
#pragma unroll
                for (int h = 0; h < NH; h++) {
                    float r = lrelu(asv[h] + adr[h] + eav * ser[h], 0.2f);
                    rw[t][h] = r;
                    lm[h] = fmaxf(lm[h], r);
                }
            }
        }
#pragma unroll
        for (int o = 1; o < 64; o <<= 1) {
#pragma unroll
            for (int h = 0; h < NH; h++) lm[h] = fmaxf(lm[h], __shfl_xor(lm[h], o, 64));
            eas += __shfl_xor(eas, o, 64);
        }
        float emean = eas / fmaxf((float)deg, 1.f);
        float m[NH], rs[NH];
        {
            const float* ap = als + (size_t)n * ALS8;
            float4 a4 = *reinterpret_cast<const float4*>(ap);
            float a5 = ap[4];
            float asv[5] = {a4.x, a4.y, a4.z, a4.w, a5};
#pragma unroll
            for (int h = 0; h < NH; h++) {
                rs[h] = lrelu(asv[h] + adr[h] + emean * ser[h], 0.2f);
                m[h] = fmaxf(lm[h], rs[h]);
            }
        }
        // ---- pass B: exp2 in registers + sum
        float ls[NH] = {0.f, 0.f, 0.f, 0.f, 0.f};
#pragma unroll
        for (int t = 0; t < 2; t++) {
            int i = lane + 64 * t;
            if (i < deg) {
#pragma unroll
                for (int h = 0; h < NH; h++) {
                    float w = exp2f(rw[t][h] - m[h]);
                    rw[t][h] = w;
                    ls[h] += w;
                }
            } else if (i == deg) {          // self-loop owner lane
                ioff_sh[i] = n * (HC * 2);
#pragma unroll
                for (int h = 0; h < NH; h++) {
                    float w = exp2f(rs[h] - m[h]);
                    rw[t][h] = w;
                    ls[h] += w;
                }
            }
        }
#pragma unroll
        for (int o = 1; o < 64; o <<= 1) {
#pragma unroll
            for (int h = 0; h < NH; h++) ls[h] += __shfl_xor(ls[h], o, 64);
        }
        float dinv[NH];
#pragma unroll
        for (int h = 0; h < NH; h++) dinv[h] = 1.f / ls[h];
        // ---- normalize: final weights -> LDS + alpha writeback
#pragma unroll
        for (int t = 0; t < 2; t++) {
            int i = lane + 64 * t;
            if (i < items) {
                int opos = (i < deg) ? myy[t] : (EE + n);
#pragma unroll
                for (int h = 0; h < NH; h++) {
                    float w = rw[t][h] * dinv[h];
                    w_sh[i * NH + h] = w;
                    alpha_out[(size_t)opos * NH + h] = w;
                }
            }
        }
        __syncthreads();                                   // [barrier #1 of 1]
        // ---- pass C: 4-deep pipelined fp16 gather via precomputed byte offsets
        if (lane < 40) {
            const char* hb = (const char*)hfeat + (size_t)(c0 * 2);
            for (int i0 = 0; i0 < items; i0 += 4) {
                float wv[4];
                uint2 hv[4];
#pragma unroll
                for (int j = 0; j < 4; j++) {
                    int i = i0 + j;
                    bool ok = i < items;
                    int ii = ok ? i : 0;
                    wv[j] = ok ? w_sh[ii * NH + hd] : 0.f;
                    hv[j] = *reinterpret_cast<const uint2*>(hb + (size_t)(unsigned)ioff_sh[ii]);
                }
#pragma unroll
                for (int j = 0; j < 4; j++) {
                    __half2 p0 = *reinterpret_cast<__half2*>(&hv[j].x);
                    __half2 p1 = *reinterpret_cast<__half2*>(&hv[j].y);
                    acc.x += wv[j] * __low2float(p0);
                    acc.y += wv[j] * __high2float(p0);
                    acc.z += wv[j] * __low2float(p1);
                    acc.w += wv[j] * __high2float(p1);
                }
            }
        }
    } else {
        // ---- slow path (deg >= CH): streaming recompute, no LDS
        float lm[NH];
#pragma unroll
        for (int h = 0; h < NH; h++) lm[h] = -3.0e38f;
        float eas = 0.f;
        for (int i = lane; i < deg; i += 64) {
            uint4 rec = erec[s0 + i];
            int src = (int)rec.x;
            float eav = __uint_as_float(rec.z);
            eas += eav;
            const float* ap = als + (size_t)src * ALS8;
            float4 a4 = *reinterpret_cast<const float4*>(ap);
            float a5 = ap[4];
            float asv[5] = {a4.x, a4.y, a4.z, a4.w, a5};
#pragma unroll
            for (int h = 0; h < NH; h++) {
                float r = lrelu(asv[h] + adr[h] + eav * ser[h], 0.2f);
                lm[h] = fmaxf(lm[h], r);
            }
        }
#pragma unroll
        for (int o = 1; o < 64; o <<= 1) {
#pragma unroll
            for (int h = 0; h < NH; h++) lm[h] = fmaxf(lm[h], __shfl_xor(lm[h], o, 64));
            eas += __shfl_xor(eas, o, 64);
        }
        float emean = eas / fmaxf((float)deg, 1.f);
        float m[NH], rs[NH];
        {
            const float* ap = als + (size_t)n * ALS8;
#pragma unroll
            for (int h = 0; h < NH; h++) {
                rs[h] = lrelu(ap[h] + adr[h] + emean * ser[h], 0.2f);
                m[h] = fmaxf(lm[h], rs[h]);
            }
        }
        float ls[NH] = {0.f, 0.f, 0.f, 0.f, 0.f};
        for (int i = lane; i < items; i += 64) {
            int src; float eav;
            if (i < deg) { uint4 rec = erec[s0 + i]; src = (int)rec.x; eav = __uint_as_float(rec.z); }
            else         { src = n; eav = emean; }
            const float* ap = als + (size_t)src * ALS8;
#pragma unroll
            for (int h = 0; h < NH; h++) {
                float r = lrelu(ap[h] + adr[h] + eav * ser[h], 0.2f);
                ls[h] += exp2f(r - m[h]);
            }
        }
#pragma unroll
        for (int o = 1; o < 64; o <<= 1) {
#pragma unroll
            for (int h = 0; h < NH; h++) ls[h] += __shfl_xor(ls[h], o, 64);
        }
        float dinv[NH];
#pragma unroll
        for (int h = 0; h < NH; h++) dinv[h] = 1.f / ls[h];
        __syncthreads();                                   // [barrier #1 of 1]
        for (int i = lane; i < items; i += 64) {
            int src; float eav; int opos;
            if (i < deg) { uint4 rec = erec[s0 + i]; src = (int)rec.x; eav = __uint_as_float(rec.z); opos = (int)rec.y; }
            else         { src = n; eav = emean; opos = EE + n; }
            const float* ap = als + (size_t)src * ALS8;
#pragma unroll
            for (int h = 0; h < NH; h++) {
                float r = lrelu(ap[h] + adr[h] + eav * ser[h], 0.2f);
                alpha_out[(size_t)opos * NH + h] = exp2f(r - m[h]) * dinv[h];
            }
        }
        if (lane < 40) {
            for (int i = 0; i < items; i++) {
                int src; float eav;
                if (i < deg) { uint4 rec = erec[s0 + i]; src = (int)rec.x; eav = __uint_as_float(rec.z); }
                else         { src = n; eav = emean; }
                float r = lrelu(als[(size_t)src * ALS8 + hd] + adr[hd] + eav * ser[hd], 0.2f);
                float w = exp2f(r - m[hd]) * dinv[hd];
                uint2 hv = *reinterpret_cast<const uint2*>(
                    &hfeat[(size_t)src * HC + c0]);
                float4 hf = h8_to_f4(hv);
                acc.x += w * hf.x; acc.y += w * hf.y;
                acc.z += w * hf.z; acc.w += w * hf.w;
            }
        }
    }

    // ---- bias + lrelu + fused LayerNorm across 160 channels (wave butterfly)
    float4 v = make_float4(0.f, 0.f, 0.f, 0.f);
    float p1 = 0.f, p2 = 0.f;
    if (lane < 40) {
        const float4 b4 = *reinterpret_cast<const float4*>(&bias[c0]);
        v.x = lrelu(acc.x + b4.x, 0.01f);
        v.y = lrelu(acc.y + b4.y, 0.01f);
        v.z = lrelu(acc.z + b4.z, 0.01f);
        v.w = lrelu(acc.w + b4.w, 0.01f);
        p1 = v.x + v.y + v.z + v.w;
        p2 = v.x * v.x + v.y * v.y + v.z * v.z + v.w * v.w;
    }
#pragma unroll
    for (int o = 1; o < 64; o <<= 1) {
        p1 += __shfl_xor(p1, o, 64);
        p2 += __shfl_xor(p2, o, 64);
    }
    float mean = p1 * (1.f / (float)HC);
    float var = p2 * (1.f / (float)HC) - mean * mean;
    float rstd = rsqrtf(var + 1e-5f);
    if (lane < 40) {
        const float4 g4 = *reinterpret_cast<const float4*>(&g_ln[c0]);
        const float4 bb = *reinterpret_cast<const float4*>(&b_ln[c0]);
        float ox = (v.x - mean) * rstd * g4.x + bb.x;
        float oy = (v.y - mean) * rstd * g4.y + bb.y;
        float oz = (v.z - mean) * rstd * g4.z + bb.z;
        float ow = (v.w - mean) * rstd * g4.w + bb.w;
        __half2 h01 = __floats2half2_rn(ox, oy);
        __half2 h23 = __floats2half2_rn(oz, ow);
        uint2 st;
        st.x = *reinterpret_cast<unsigned*>(&h01);
        st.y = *reinterpret_cast<unsigned*>(&h23);
        *reinterpret_cast<uint2*>(&x_out[(size_t)n * HC + c0]) = st;
    }
}

// -------- x3 = lrelu(x2 @ mw + mb) (x2 fp16); 48x160 tiles, 8x4 per-thread;
//          fused pooled partial sums (batch sorted, rows per thread consecutive)
__global__ __launch_bounds__(256, 5) void gemm3_kernel(const __half* __restrict__ A,
                                                       const float* __restrict__ W,
                                                       const float* __restrict__ bias,
                                                       const int* __restrict__ batch,
                                                       float* __restrict__ x3,
                                                       float* __restrict__ psum) {
    __shared__ float As[32 * ASTR2];
    __shared__ float Bs[32 * 160];
    __shared__ int bt[RB];
    const int tid = threadIdx.x;
    const int base = blockIdx.x * RB;
    const int cg = tid % 40;
    const int rg = tid / 40;
    const bool active = tid < 240;

    if (tid < RB) bt[tid] = batch[(base + tid < NN) ? (base + tid) : (NN - 1)];

    float acc[8][4];
#pragma unroll
    for (int r = 0; r < 8; r++)
#pragma unroll
        for (int j = 0; j < 4; j++) acc[r][j] = 0.f;

    for (int k0 = 0; k0 < HC; k0 += 32) {
        __syncthreads();
        for (int f = tid; f < 384; f += 256) {
            int srow = f >> 3, skq = f & 7;
            float4 av = make_float4(0.f, 0.f, 0.f, 0.f);
            if (base + srow < NN) {
                const __half* ap = A + (size_t)(base + srow) * HC + k0 + skq * 4;
                av = h8_to_f4(*reinterpret_cast<const uint2*>(ap));
            }
            As[(skq * 4 + 0) * ASTR2 + srow] = av.x;
            As[(skq * 4 + 1) * ASTR2 + srow] = av.y;
            As[(skq * 4 + 2) * ASTR2 + srow] = av.z;
            As[(skq * 4 + 3) * ASTR2 + srow] = av.w;
        }
#pragma unroll
        for (int i = 0; i < 5; i++) {
            int f = tid + 256 * i;
            int kk = f / 40, c4 = f - kk * 40;
            *reinterpret_cast<float4*>(&Bs[kk * 160 + c4 * 4]) =
                *reinterpret_cast<const float4*>(&W[(size_t)(k0 + kk) * HC + c4 * 4]);
        }
        __syncthreads();
        if (active) {
#pragma unroll 8
            for (int k = 0; k < 32; k++) {
                const float4 b = *reinterpret_cast<const float4*>(&Bs[k * 160 + cg * 4]);
                const float4 a0 = *reinterpret_cast<const float4*>(&As[k * ASTR2 + rg * 8]);
                const float4 a1 = *reinterpret_cast<const float4*>(&As[k * ASTR2 + rg * 8 + 4]);
#define FMA4(rr, av) acc[rr][0] += (av) * b.x; acc[rr][1] += (av) * b.y; \
                     acc[rr][2] += (av) * b.z; acc[rr][3] += (av) * b.w;
                FMA4(0, a0.x) FMA4(1, a0.y) FMA4(2, a0.z) FMA4(3, a0.w)
                FMA4(4, a1.x) FMA4(5, a1.y) FMA4(6, a1.z) FMA4(7, a1.w)
#undef FMA4
            }
        }
    }
    if (active) {
        float4 b4 = *reinterpret_cast<const float4*>(&bias[cg * 4]);
        float run[4] = {0.f, 0.f, 0.f, 0.f};
        int g = bt[rg * 8];
#pragma unroll
        for (int r = 0; r < 8; r++) {
            int grow = base + rg * 8 + r;
            bool ok = grow < NN;
            float4 vv;
            vv.x = lrelu(acc[r][0] + b4.x, 0.01f);
            vv.y = lrelu(acc[r][1] + b4.y, 0.01f);
            vv.z = lrelu(acc[r][2] + b4.z, 0.01f);
            vv.w = lrelu(acc[r][3] + b4.w, 0.01f);
            if (ok) *reinterpret_cast<float4*>(&x3[(size_t)grow * HC + cg * 4]) = vv;
            int gb = bt[rg * 8 + r];
            if (gb != g) {
                atomicAdd(&psum[g * HC + cg * 4 + 0], run[0]);
                atomicAdd(&psum[g * HC + cg * 4 + 1], run[1]);
                atomicAdd(&psum[g * HC + cg * 4 + 2], run[2]);
                atomicAdd(&psum[g * HC + cg * 4 + 3], run[3]);
                run[0] = run[1] = run[2] = run[3] = 0.f;
                g = gb;
            }
            if (ok) { run[0] += vv.x; run[1] += vv.y; run[2] += vv.z; run[3] += vv.w; }
        }
        atomicAdd(&psum[g * HC + cg * 4 + 0], run[0]);
        atomicAdd(&psum[g * HC + cg * 4 + 1], run[1]);
        atomicAdd(&psum[g * HC + cg * 4 + 2], run[2]);
        atomicAdd(&psum[g * HC + cg * 4 + 3], run[3]);
    }
}

__global__ void pooldiv_kernel(const float* __restrict__ psum, const int* __restrict__ gcnt,
                               float* pooled_out) {
    int i = blockIdx.x * 256 + threadIdx.x;
    if (i < NG * HC) pooled_out[i] = psum[i] / fmaxf((float)gcnt[i / HC], 1.f);
}

// ---------------------------------------------------------------------- launch
extern "C" void kernel_launch(void* const* d_in, const int* in_sizes, int n_in,
                              void* d_out, int out_size, void* d_ws, size_t ws_size,
                              hipStream_t stream) {
    const float* x    = (const float*)d_in[0];
    const int*   ei   = (const int*)d_in[1];
    const float* ea   = (const float*)d_in[2];
    const int*   batch= (const int*)d_in[3];
    const float* w1   = (const float*)d_in[4];
    const float* we1  = (const float*)d_in[5];
    const float* as1  = (const float*)d_in[6];
    const float* ad1  = (const float*)d_in[7];
    const float* ae1  = (const float*)d_in[8];
    const float* b1   = (const float*)d_in[9];
    const float* w2   = (const float*)d_in[10];
    const float* we2  = (const float*)d_in[11];
    const float* as2  = (const float*)d_in[12];
    const float* ad2  = (const float*)d_in[13];
    const float* ae2  = (const float*)d_in[14];
    const float* b2   = (const float*)d_in[15];
    const float* ln1g = (const float*)d_in[16];
    const float* ln1b = (const float*)d_in[17];
    const float* ln2g = (const float*)d_in[18];
    const float* ln2b = (const float*)d_in[19];
    const float* mw   = (const float*)d_in[20];
    const float* mb   = (const float*)d_in[21];

    float* out = (float*)d_out;
    float* pooled_out = out + (size_t)NN * HC;
    float* a1 = pooled_out + NG * HC;
    float* a2 = a1 + (size_t)(EE + NN) * NH;

    char* wp = (char*)d_ws;
    auto alloc = [&](size_t bytes) {
        void* p = (void*)wp;
        wp += (bytes + 255) & ~(size_t)255;
        return p;
    };
    // 32MB region, triple-overlaid in time:
    //   [0..8)   hist_g   (dead after sscan)     -> [0..16)  h fp16
    //   [8..24)  base_g   (dead after scatter)   -> [16..32) x12h fp16
    char* region = (char*)alloc(32 * 1024 * 1024);
    __half* hbuf = (__half*)region;                               // 16 MB fp16 h
    __half* x12h = (__half*)(region + 16 * 1024 * 1024);          // 16 MB fp16 x1/x2
    unsigned*       hist_g = (unsigned*)region;                   // 8 MB
    unsigned short* base_g = (unsigned short*)(region + 8 * 1024 * 1024); // 16 MB
    uint4* erec  = (uint4*)alloc((size_t)EE * 16);       // 12.8 MB
    float* als   = (float*)alloc((size_t)NN * ALS8 * 4); // padded al_s
    float* ald   = (float*)alloc((size_t)NN * NH * 4);
    int*   deg   = (int*)alloc((size_t)NN * 4);
    int*   soff  = (int*)alloc((size_t)(NN + 1) * 4);
    float* sbuf  = (float*)alloc(64);
    float* psum  = (float*)alloc((size_t)NG * HC * 4);
    int*   gcnt  = (int*)alloc((size_t)NG * 4);
    int*   bsum  = (int*)alloc(256 * 4);
    int*   boff  = (int*)alloc(256 * 4);

    const int GB = (NN + RB - 1) / RB;   // 1042 gemm blocks

    prep_kernel<<<40, 256, 0, stream>>>(batch, psum, gcnt, we1, ae1, we2, ae2, sbuf);
    hist_kernel<<<NB, 256, 0, stream>>>(ei, hist_g);
    sscan_kernel<<<49, 256, 0, stream>>>(hist_g, base_g, deg);
    scan1_kernel<<<196, 256, 0, stream>>>(deg, bsum);
    scan2_kernel<<<1, 256, 0, stream>>>(bsum, boff);
    scan3_kernel<<<196, 256, 0, stream>>>(deg, boff, soff);
    scatter_kernel<<<NB, 256, 0, stream>>>(ei, ea, base_g, soff, erec);

    gemm_kernel<128, float><<<GB, 256, 0, stream>>>(x, w1, as1, ad1, hbuf, als, ald);
    aggregate_kernel<<<12500, 256, 0, stream>>>(soff, erec, hbuf, als, ald,
                                                sbuf, b1, ln1g, ln1b, a1, x12h);

    gemm_kernel<160, __half><<<GB, 256, 0, stream>>>(x12h, w2, as2, ad2, hbuf, als, ald);
    aggregate_kernel<<<12500, 256, 0, stream>>>(soff, erec, hbuf, als, ald,
                                                sbuf + 5, b2, ln2g, ln2b, a2, x12h);

    gemm3_kernel<<<GB, 256, 0, stream>>>(x12h, mw, mb, batch, out, psum);
    pooldiv_kernel<<<40, 256, 0, stream>>>(psum, gcnt, pooled_out);
}

// Round 8
// 447.276 us; speedup vs baseline: 1.2449x; 1.1031x over previous
//
#include <hip/hip_runtime.h>
#include <hip/hip_fp16.h>
#include <math.h>

#define NN 50000
#define EE 800000
#define FIN 128
#define NH 5
#define HC 160
#define NG 64
#define CH 128        // fast-path max items per node (deg <= 127)
#define NB 160        // sort blocks
#define EPB 5000      // edges per sort block (NB*EPB == EE)
#define NW 12500      // packed histogram words (4 byte-bins per word)
#define ALS8 8        // padded stride for al_s (float4 + float loads)
#define LOG2E 1.4426950408889634f

typedef _Float16 f16x8 __attribute__((ext_vector_type(8)));
typedef _Float16 f16x4 __attribute__((ext_vector_type(4)));
typedef float f32x4 __attribute__((ext_vector_type(4)));

__device__ __forceinline__ float lrelu(float x, float s) { return x >= 0.f ? x : s * x; }

// unpack 4 consecutive fp16 (8B) to float4
__device__ __forceinline__ float4 h8_to_f4(uint2 u) {
    __half2 a = *reinterpret_cast<__half2*>(&u.x);
    __half2 b = *reinterpret_cast<__half2*>(&u.y);
    float2 fa = __half22float2(a), fb = __half22float2(b);
    return make_float4(fa.x, fa.y, fb.x, fb.y);
}

// ---------------- psum zero + per-graph node counts + per-layer s[h] (merged preps)
__global__ void prep_kernel(const int* __restrict__ batch, float* psum, int* gcnt,
                            const float* we1, const float* ae1,
                            const float* we2, const float* ae2, float* s_out) {
    int i = blockIdx.x * 256 + threadIdx.x;
    if (i < NG * HC) psum[i] = 0.f;
    if (i < NG) {
        int lo = 0, hi = NN;
        while (lo < hi) { int m = (lo + hi) >> 1; if (batch[m] < i) lo = m + 1; else hi = m; }
        int s = lo;
        lo = 0; hi = NN;
        int g1 = i + 1;
        while (lo < hi) { int m = (lo + hi) >> 1; if (batch[m] < g1) lo = m + 1; else hi = m; }
        gcnt[i] = lo - s;
    }
    if (i < 10) {
        const float* we = (i < 5) ? we1 : we2;
        const float* ae = (i < 5) ? ae1 : ae2;
        int h = i % 5;
        float s = 0.f;
        for (int c = 0; c < 32; c++) s += we[h * 32 + c] * ae[h * 32 + c];
        s_out[i] = s * LOG2E;          // exp2-domain
    }
}

// ---------------- W -> W^T fp16 (B-operands for MFMA): wt[c][k] = W[k][c]
__global__ void prepw_kernel(const float* __restrict__ w1, const float* __restrict__ w2,
                             const float* __restrict__ mw,
                             __half* wt1, __half* wt2, __half* wt3) {
    int i = blockIdx.x * 256 + threadIdx.x;
    if (i < 160 * 128) {
        int c = i >> 7, k = i & 127;
        wt1[i] = __float2half(w1[k * HC + c]);
    }
    if (i < 160 * 160) {
        int c = i / 160, k = i - c * 160;
        wt2[i] = __float2half(w2[k * HC + c]);
        wt3[i] = __float2half(mw[k * HC + c]);
    }
}

// ---------------- per-block LDS histogram of dst (byte-packed, no global atomics)
__global__ __launch_bounds__(256) void hist_kernel(const int* __restrict__ ei,
                                                   unsigned* __restrict__ hist_g) {
    __shared__ unsigned lh[NW];
    int b = blockIdx.x, tid = threadIdx.x;
    for (int w = tid; w < NW; w += 256) lh[w] = 0;
    __syncthreads();
    const int* dstp = ei + EE + b * EPB;
    for (int i = tid; i < EPB; i += 256) {
        int d = dstp[i];
        atomicAdd(&lh[d >> 2], 1u << ((d & 3) * 8));
    }
    __syncthreads();
    unsigned* outp = hist_g + (size_t)b * NW;
    for (int w = tid; w < NW; w += 256) outp[w] = lh[w];
}

// ---------------- column scan over blocks: per-(block,bin) base + total deg
__global__ void sscan_kernel(const unsigned* __restrict__ hist_g,
                             unsigned short* __restrict__ base_g, int* __restrict__ deg) {
    int w = blockIdx.x * 256 + threadIdx.x;
    if (w >= NW) return;
    unsigned r0 = 0, r1 = 0, r2 = 0, r3 = 0;
    for (int b = 0; b < NB; b++) {
        unsigned x = hist_g[(size_t)b * NW + w];
        uint2 st;
        st.x = r0 | (r1 << 16);
        st.y = r2 | (r3 << 16);
        *reinterpret_cast<uint2*>(&base_g[(size_t)b * NN + 4 * w]) = st;
        r0 += x & 0xffu; r1 += (x >> 8) & 0xffu; r2 += (x >> 16) & 0xffu; r3 += (x >> 24) & 0xffu;
    }
    uint4 dv; dv.x = r0; dv.y = r1; dv.z = r2; dv.w = r3;
    *reinterpret_cast<uint4*>(&deg[4 * w]) = dv;
}

// ------------------------------------------------------- 3-phase parallel scan
__global__ void scan1_kernel(const int* __restrict__ deg, int* bsum) {
    __shared__ int ws[4];
    int tid = threadIdx.x, lane = tid & 63, wid = tid >> 6;
    int i = blockIdx.x * 256 + tid;
    int v = (i < NN) ? deg[i] : 0;
    for (int o = 32; o >= 1; o >>= 1) v += __shfl_down(v, o, 64);
    if (lane == 0) ws[wid] = v;
    __syncthreads();
    if (tid == 0) bsum[blockIdx.x] = ws[0] + ws[1] + ws[2] + ws[3];
}

__global__ void scan2_kernel(int* bsum, int* boff) {
    __shared__ int ws[4];
    int tid = threadIdx.x, lane = tid & 63, wid = tid >> 6;
    int v = (tid < 196) ? bsum[tid] : 0;
    int x = v;
    for (int o = 1; o < 64; o <<= 1) {
        int t = __shfl_up(x, o, 64);
        if (lane >= o) x += t;
    }
    if (lane == 63) ws[wid] = x;
    __syncthreads();
    if (tid == 0) {
        int acc = 0;
        for (int w = 0; w < 4; w++) { int t = ws[w]; ws[w] = acc; acc += t; }
    }
    __syncthreads();
    if (tid < 196) boff[tid] = x + ws[wid] - v;
}

__global__ void scan3_kernel(const int* __restrict__ deg, const int* __restrict__ boff,
                             int* off) {
    __shared__ int ws[4];
    int tid = threadIdx.x, lane = tid & 63, wid = tid >> 6;
    int i = blockIdx.x * 256 + tid;
    int v = (i < NN) ? deg[i] : 0;
    int x = v;
    for (int o = 1; o < 64; o <<= 1) {
        int t = __shfl_up(x, o, 64);
        if (lane >= o) x += t;
    }
    if (lane == 63) ws[wid] = x;
    __syncthreads();
    if (tid == 0) {
        int acc = 0;
        for (int w = 0; w < 4; w++) { int t = ws[w]; ws[w] = acc; acc += t; }
    }
    __syncthreads();
    int incl = x + ws[wid] + boff[blockIdx.x];
    if (i < NN) off[i + 1] = incl;
    if (i == 0) off[0] = 0;
}

// ---------------- rank via LDS + write packed edge record (no global atomics)
__global__ __launch_bounds__(256) void scatter_kernel(const int* __restrict__ ei,
                                                      const float* __restrict__ ea,
                                                      const unsigned short* __restrict__ base_g,
                                                      const int* __restrict__ soff,
                                                      uint4* __restrict__ erec) {
    __shared__ unsigned lc[NW];
    int b = blockIdx.x, tid = threadIdx.x;
    for (int w = tid; w < NW; w += 256) lc[w] = 0;
    __syncthreads();
    int e0 = b * EPB;
    const unsigned short* brow = base_g + (size_t)b * NN;
    for (int i = tid; i < EPB; i += 256) {
        int e = e0 + i;
        int d = ei[EE + e];
        int sh = (d & 3) * 8;
        unsigned old = atomicAdd(&lc[d >> 2], 1u << sh);
        int r = (int)((old >> sh) & 0xffu);
        int pos = soff[d] + (int)brow[d] + r;
        uint4 rec;
        rec.x = (unsigned)ei[e];
        rec.y = (unsigned)e;
        rec.z = __float_as_uint(ea[e]);
        rec.w = 0;
        erec[pos] = rec;
    }
}

// ---------------- MFMA GEMM: h = A @ W (K = 128 or 160), 32 rows x 160 cols per
//   128-thread block (2 waves).  Wave w: 32 rows x 80 cols = 2x5 mfma 16x16x32
//   tiles, fp16 inputs / fp32 accum.  W pre-transposed fp16 (Wt[c][k]).
//   h -> LDS -> coalesced fp16 store; att-dots read h from LDS.
template <int K, typename AT>
__global__ __launch_bounds__(128, 3) void gemm_kernel(const AT* __restrict__ A,
                                                      const __half* __restrict__ Wt,
                                                      const float* __restrict__ a_s,
                                                      const float* __restrict__ a_d,
                                                      __half* __restrict__ out,
                                                      float* __restrict__ al_s,
                                                      float* __restrict__ al_d) {
    __shared__ __align__(16) _Float16 Alds[32 * 40];     // [row][k] pad 40
    __shared__ __align__(16) _Float16 Bt[160 * 40];      // [col][k] pad 40
    __shared__ __align__(16) _Float16 Clds[2 * 32 * 88]; // per-wave [row][col] pad 88
    __shared__ float asld[160], adld[160];
    const int tid = threadIdx.x;
    const int w = tid >> 6, l = tid & 63;
    const int lr = l & 15, lq = l >> 4;
    const int base = blockIdx.x * 32;

    // FIX (R7 bug): 128-thread block — stride the 160-entry staging loop.
    for (int i = tid; i < 160; i += 128) { asld[i] = a_s[i]; adld[i] = a_d[i]; }

    f32x4 acc[2][5];
#pragma unroll
    for (int mt = 0; mt < 2; mt++)
#pragma unroll
        for (int t = 0; t < 5; t++) acc[mt][t] = (f32x4){0.f, 0.f, 0.f, 0.f};

    for (int k0 = 0; k0 < K; k0 += 32) {
        __syncthreads();
        // ---- stage A (fp16, [row][k])
        if constexpr (sizeof(AT) == 4) {
            for (int f = tid; f < 256; f += 128) {
                int row = f >> 3, q = f & 7;
                float4 av = make_float4(0.f, 0.f, 0.f, 0.f);
                if (base + row < NN)
                    av = *reinterpret_cast<const float4*>(&A[(size_t)(base + row) * K + k0 + q * 4]);
                f16x4 hv = {(_Float16)av.x, (_Float16)av.y, (_Float16)av.z, (_Float16)av.w};
                *reinterpret_cast<f16x4*>(&Alds[row * 40 + q * 4]) = hv;
            }
        } else {
            int row = tid >> 2, q = tid & 3;
            uint4 v = make_uint4(0, 0, 0, 0);
            if (base + row < NN)
                v = *reinterpret_cast<const uint4*>(&A[(size_t)(base + row) * K + k0 + q * 8]);
            *reinterpret_cast<uint4*>(&Alds[row * 40 + q * 8]) = v;
        }
        // ---- stage B^T ([col][k]) from Wt fp16
        for (int f = tid; f < 640; f += 128) {
            int c = f >> 2, q = f & 3;
            uint4 v = *reinterpret_cast<const uint4*>(&Wt[(size_t)c * K + k0 + q * 8]);
            *reinterpret_cast<uint4*>(&Bt[c * 40 + q * 8]) = v;
        }
        __syncthreads();
        const f16x8 a0 = *reinterpret_cast<const f16x8*>(&Alds[lr * 40 + lq * 8]);
        const f16x8 a1 = *reinterpret_cast<const f16x8*>(&Alds[(16 + lr) * 40 + lq * 8]);
#pragma unroll
        for (int t = 0; t < 5; t++) {
            const f16x8 b = *reinterpret_cast<const f16x8*>(
                &Bt[((w * 5 + t) * 16 + lr) * 40 + lq * 8]);
            acc[0][t] = __builtin_amdgcn_mfma_f32_16x16x32_f16(a0, b, acc[0][t], 0, 0, 0);
            acc[1][t] = __builtin_amdgcn_mfma_f32_16x16x32_f16(a1, b, acc[1][t], 0, 0, 0);
        }
    }
    // ---- C -> LDS (D layout: col = lane&15, row = (lane>>4)*4 + j)
    _Float16* Cw = Clds + w * (32 * 88);
#pragma unroll
    for (int mt = 0; mt < 2; mt++)
#pragma unroll
        for (int t = 0; t < 5; t++)
#pragma unroll
            for (int j = 0; j < 4; j++)
                Cw[(mt * 16 + lq * 4 + j) * 88 + t * 16 + lr] = (_Float16)acc[mt][t][j];
    __syncthreads();
    // ---- coalesced h store (fp16, 16B per thread-chunk)
    for (int i = l; i < 320; i += 64) {
        int row = i / 10, q = i - row * 10;
        if (base + row < NN) {
            uint4 v = *reinterpret_cast<const uint4*>(&Cw[row * 88 + q * 8]);
            *reinterpret_cast<uint4*>(&out[(size_t)(base + row) * HC + w * 80 + q * 8]) = v;
        }
    }
    // ---- att dots from Clds (both wave regions), exp2-domain
    for (int f = tid; f < 320; f += 128) {
        int row = f / 10, rem = f - row * 10;
        int h = rem >> 1, sd = rem & 1;
        if (base + row < NN) {
            const float* av = (sd ? adld : asld) + h * 32;
            float s = 0.f;
#pragma unroll
            for (int c = 0; c < 32; c++) {
                int col = h * 32 + c;
                int wv = col >= 80;
                s += (float)Clds[wv * (32 * 88) + row * 88 + (col - 80 * wv)] * av[c];
            }
            s *= LOG2E;
            if (sd) al_d[(size_t)(base + row) * NH + h] = s;
            else    al_s[(size_t)(base + row) * ALS8 + h] = s;
        }
    }
}

// ------------- per-node (one WAVE per node, 4 nodes per block): segment softmax
//               (exp2-domain) + weighted fp16 gather + bias/lrelu/LN -> fp16 x_out.
//               Exactly ONE __syncthreads on both paths.
__global__ __launch_bounds__(256, 8) void aggregate_kernel(
    const int* __restrict__ soff, const uint4* __restrict__ erec,
    const __half* __restrict__ hfeat, const float* __restrict__ als,
    const float* __restrict__ al_d, const float* __restrict__ s_e,
    const float* __restrict__ bias, const float* __restrict__ g_ln,
    const float* __restrict__ b_ln,
    float* __restrict__ alpha_out, __half* __restrict__ x_out) {
    const int wave = threadIdx.x >> 6;
    const int lane = threadIdx.x & 63;
    const int n = blockIdx.x * 4 + wave;
    __shared__ float w_sh_all[4][CH * NH];
    __shared__ int ioff_all[4][CH];      // byte offsets into hfeat (src*HC*2)
    float* w_sh = w_sh_all[wave];
    int* ioff_sh = ioff_all[wave];

    const int s0 = soff[n];
    const int deg = soff[n + 1] - s0;
    const int items = deg + 1;

    float adr[NH], ser[NH];
#pragma unroll
    for (int h = 0; h < NH; h++) { adr[h] = al_d[n * NH + h]; ser[h] = s_e[h]; }

    const int c0 = 4 * lane;      // lanes 0..39 own channels c0..c0+3
    const int hd = lane >> 3;     // head for those channels (valid for lane<40)
    float4 acc = make_float4(0.f, 0.f, 0.f, 0.f);

    if (items <= CH) {
        // ---- pass A: logits into registers (2 tiles x 5 heads), per-head max, ea sum
        float rw[2][NH];
        float lm[NH];
#pragma unroll
        for (int h = 0; h < NH; h++) lm[h] = -3.0e38f;
        float eas = 0.f;
        int myy[2];
#pragma unroll
        for (int t = 0; t < 2; t++) {
            int i = lane + 64 * t;
            if (i < deg) {
                uint4 rec = erec[s0 + i];
                int src = (int)rec.x;
                float eav = __uint_as_float(rec.z);
                ioff_sh[i] = src * (HC * 2);
                myy[t] = (int)rec.y;
                eas += eav;
                const float* ap = als + (size_t)src * ALS8;
                float4 a4 = *reinterpret_cast<const float4*>(ap);
                float a5 = ap[4];
                float asv[5] = {a4.x, a4.y, a4.z, a4.w, a5};
#pragma unroll
                for (int h = 0; h < NH; h++) {
                    float r = lrelu(asv[h] + adr[h] + eav * ser[h], 0.2f);
                    rw[t][h] = r;
                    lm[h] = fmaxf(lm[h], r);
                }
            }
        }
#pragma unroll
        for (int o = 1; o < 64; o <<= 1) {
#pragma unroll
            for (int h = 0; h < NH; h++) lm[h] = fmaxf(lm[h], __shfl_xor(lm[h], o, 64));
            eas += __shfl_xor(eas, o, 64);
        }
        float emean = eas / fmaxf((float)deg, 1.f);
        float m[NH], rs[NH];
        {
            const float* ap = als + (size_t)n * ALS8;
            float4 a4 = *reinterpret_cast<const float4*>(ap);
            float a5 = ap[4];
            float asv[5] = {a4.x, a4.y, a4.z, a4.w, a5};
#pragma unroll
            for (int h = 0; h < NH; h++) {
                rs[h] = lrelu(asv[h] + adr[h] + emean * ser[h], 0.2f);
                m[h] = fmaxf(lm[h], rs[h]);
            }
        }
        // ---- pass B: exp2 in registers + sum
        float ls[NH] = {0.f, 0.f, 0.f, 0.f, 0.f};
#pragma unroll
        for (int t = 0; t < 2; t++) {
            int i = lane + 64 * t;
            if (i < deg) {
#pragma unroll
                for (int h = 0; h < NH; h++) {
                    float w = exp2f(rw[t][h] - m[h]);
                    rw[t][h] = w;
                    ls[h] += w;
                }
            } else if (i == deg) {          // self-loop owner lane
                ioff_sh[i] = n * (HC * 2);
#pragma unroll
                for (int h = 0; h < NH; h++) {
                    float w = exp2f(rs[h] - m[h]);
                    rw[t][h] = w;
                    ls[h] += w;
                }
            }
        }
#pragma unroll
        for (int o = 1; o < 64; o <<= 1) {
#pragma unroll
            for (int h = 0; h < NH; h++) ls[h] += __shfl_xor(ls[h], o, 64);
        }
        float dinv[NH];
#pragma unroll
        for (int h = 0; h < NH; h++) dinv[h] = 1.f / ls[h];
        // ---- normalize: final weights -> LDS + alpha writeback
#pragma unroll
        for (int t = 0; t < 2; t++) {
            int i = lane + 64 * t;
            if (i < items) {
                int opos = (i < deg) ? myy[t] : (EE + n);
#pragma unroll
                for (int h = 0; h < NH; h++) {
                    float w = rw[t][h] * dinv[h];
                    w_sh[i * NH + h] = w;
                    alpha_out[(size_t)opos * NH + h] = w;
                }
            }
        }
        __syncthreads();                                   // [barrier #1 of 1]
        // ---- pass C: 4-deep pipelined fp16 gather via precomputed byte offsets
        if (lane < 40) {
            const char* hb = (const char*)hfeat + (size_t)(c0 * 2);
            for (int i0 = 0; i0 < items; i0 += 4) {
                float wv[4];
                uint2 hv[4];
#pragma unroll
                for (int j = 0; j < 4; j++) {
                    int i = i0 + j;
                    bool ok = i < items;
                    int ii = ok ? i : 0;
                    wv[j] = ok ? w_sh[ii * NH + hd] : 0.f;
                    hv[j] = *reinterpret_cast<const uint2*>(hb + (size_t)(unsigned)ioff_sh[ii]);
                }
#pragma unroll
                for (int j = 0; j < 4; j++) {
                    __half2 p0 = *reinterpret_cast<__half2*>(&hv[j].x);
                    __half2 p1 = *reinterpret_cast<__half2*>(&hv[j].y);
                    acc.x += wv[j] * __low2float(p0);
                    acc.y += wv[j] * __high2float(p0);
                    acc.z += wv[j] * __low2float(p1);
                    acc.w += wv[j] * __high2float(p1);
                }
            }
        }
    } else {
        // ---- slow path (deg >= CH): streaming recompute, no LDS
        float lm[NH];
#pragma unroll
        for (int h = 0; h < NH; h++) lm[h] = -3.0e38f;
        float eas = 0.f;
        for (int i = lane; i < deg; i += 64) {
            uint4 rec = erec[s0 + i];
            int src = (int)rec.x;
            float eav = __uint_as_float(rec.z);
            eas += eav;
            const float* ap = als + (size_t)src * ALS8;
            float4 a4 = *reinterpret_cast<const float4*>(ap);
            float a5 = ap[4];
            float asv[5] = {a4.x, a4.y, a4.z, a4.w, a5};
#pragma unroll
            for (int h = 0; h < NH; h++) {
                float r = lrelu(asv[h] + adr[h] + eav * ser[h], 0.2f);
                lm[h] = fmaxf(lm[h], r);
            }
        }
#pragma unroll
        for (int o = 1; o < 64; o <<= 1) {
#pragma unroll
            for (int h = 0; h < NH; h++) lm[h] = fmaxf(lm[h], __shfl_xor(lm[h], o, 64));
            eas += __shfl_xor(eas, o, 64);
        }
        float emean = eas / fmaxf((float)deg, 1.f);
        float m[NH], rs[NH];
        {
            const float* ap = als + (size_t)n * ALS8;
#pragma unroll
            for (int h = 0; h < NH; h++) {
                rs[h] = lrelu(ap[h] + adr[h] + emean * ser[h], 0.2f);
                m[h] = fmaxf(lm[h], rs[h]);
            }
        }
        float ls[NH] = {0.f, 0.f, 0.f, 0.f, 0.f};
        for (int i = lane; i < items; i += 64) {
            int src; float eav;
            if (i < deg) { uint4 rec = erec[s0 + i]; src = (int)rec.x; eav = __uint_as_float(rec.z); }
            else         { src = n; eav = emean; }
            const float* ap = als + (size_t)src * ALS8;
#pragma unroll
            for (int h = 0; h < NH; h++) {
                float r = lrelu(ap[h] + adr[h] + eav * ser[h], 0.2f);
                ls[h] += exp2f(r - m[h]);
            }
        }
#pragma unroll
        for (int o = 1; o < 64; o <<= 1) {
#pragma unroll
            for (int h = 0; h < NH; h++) ls[h] += __shfl_xor(ls[h], o, 64);
        }
        float dinv[NH];
#pragma unroll
        for (int h = 0; h < NH; h++) dinv[h] = 1.f / ls[h];
        __syncthreads();                                   // [barrier #1 of 1]
        for (int i = lane; i < items; i += 64) {
            int src; float eav; int opos;
            if (i < deg) { uint4 rec = erec[s0 + i]; src = (int)rec.x; eav = __uint_as_float(rec.z); opos = (int)rec.y; }
            else         { src = n; eav = emean; opos = EE + n; }
            const float* ap = als + (size_t)src * ALS8;
#pragma unroll
            for (int h = 0; h < NH; h++) {
                float r = lrelu(ap[h] + adr[h] + eav * ser[h], 0.2f);
                alpha_out[(size_t)opos * NH + h] = exp2f(r - m[h]) * dinv[h];
            }
        }
        if (lane < 40) {
            for (int i = 0; i < items; i++) {
                int src; float eav;
                if (i < deg) { uint4 rec = erec[s0 + i]; src = (int)rec.x; eav = __uint_as_float(rec.z); }
                else         { src = n; eav = emean; }
                float r = lrelu(als[(size_t)src * ALS8 + hd] + adr[hd] + eav * ser[hd], 0.2f);
                float w = exp2f(r - m[hd]) * dinv[hd];
                uint2 hv = *reinterpret_cast<const uint2*>(
                    &hfeat[(size_t)src * HC + c0]);
                float4 hf = h8_to_f4(hv);
                acc.x += w * hf.x; acc.y += w * hf.y;
                acc.z += w * hf.z; acc.w += w * hf.w;
            }
        }
    }

    // ---- bias + lrelu + fused LayerNorm across 160 channels (wave butterfly)
    float4 v = make_float4(0.f, 0.f, 0.f, 0.f);
    float p1 = 0.f, p2 = 0.f;
    if (lane < 40) {
        const float4 b4 = *reinterpret_cast<const float4*>(&bias[c0]);
        v.x = lrelu(acc.x + b4.x, 0.01f);
        v.y = lrelu(acc.y + b4.y, 0.01f);
        v.z = lrelu(acc.z + b4.z, 0.01f);
        v.w = lrelu(acc.w + b4.w, 0.01f);
        p1 = v.x + v.y + v.z + v.w;
        p2 = v.x * v.x + v.y * v.y + v.z * v.z + v.w * v.w;
    }
#pragma unroll
    for (int o = 1; o < 64; o <<= 1) {
        p1 += __shfl_xor(p1, o, 64);
        p2 += __shfl_xor(p2, o, 64);
    }
    float mean = p1 * (1.f / (float)HC);
    float var = p2 * (1.f / (float)HC) - mean * mean;
    float rstd = rsqrtf(var + 1e-5f);
    if (lane < 40) {
        const float4 g4 = *reinterpret_cast<const float4*>(&g_ln[c0]);
        const float4 bb = *reinterpret_cast<const float4*>(&b_ln[c0]);
        float ox = (v.x - mean) * rstd * g4.x + bb.x;
        float oy = (v.y - mean) * rstd * g4.y + bb.y;
        float oz = (v.z - mean) * rstd * g4.z + bb.z;
        float ow = (v.w - mean) * rstd * g4.w + bb.w;
        __half2 h01 = __floats2half2_rn(ox, oy);
        __half2 h23 = __floats2half2_rn(oz, ow);
        uint2 st;
        st.x = *reinterpret_cast<unsigned*>(&h01);
        st.y = *reinterpret_cast<unsigned*>(&h23);
        *reinterpret_cast<uint2*>(&x_out[(size_t)n * HC + c0]) = st;
    }
}

// -------- x3 = lrelu(x2 @ mw + mb) (MFMA, x2 fp16); direct fp32 store + pooled
__global__ __launch_bounds__(128, 3) void gemm3_kernel(const __half* __restrict__ A,
                                                       const __half* __restrict__ Wt,
                                                       const float* __restrict__ bias,
                                                       const int* __restrict__ batch,
                                                       float* __restrict__ x3,
                                                       float* __restrict__ psum) {
    __shared__ __align__(16) _Float16 Alds[32 * 40];
    __shared__ __align__(16) _Float16 Bt[160 * 40];
    __shared__ int bt[32];
    const int tid = threadIdx.x;
    const int w = tid >> 6, l = tid & 63;
    const int lr = l & 15, lq = l >> 4;
    const int base = blockIdx.x * 32;

    if (tid < 32) bt[tid] = batch[(base + tid < NN) ? (base + tid) : (NN - 1)];

    f32x4 acc[2][5];
#pragma unroll
    for (int mt = 0; mt < 2; mt++)
#pragma unroll
        for (int t = 0; t < 5; t++) acc[mt][t] = (f32x4){0.f, 0.f, 0.f, 0.f};

    for (int k0 = 0; k0 < HC; k0 += 32) {
        __syncthreads();
        {
            int row = tid >> 2, q = tid & 3;
            uint4 v = make_uint4(0, 0, 0, 0);
            if (base + row < NN)
                v = *reinterpret_cast<const uint4*>(&A[(size_t)(base + row) * HC + k0 + q * 8]);
            *reinterpret_cast<uint4*>(&Alds[row * 40 + q * 8]) = v;
        }
        for (int f = tid; f < 640; f += 128) {
            int c = f >> 2, q = f & 3;
            uint4 v = *reinterpret_cast<const uint4*>(&Wt[(size_t)c * HC + k0 + q * 8]);
            *reinterpret_cast<uint4*>(&Bt[c * 40 + q * 8]) = v;
        }
        __syncthreads();
        const f16x8 a0 = *reinterpret_cast<const f16x8*>(&Alds[lr * 40 + lq * 8]);
        const f16x8 a1 = *reinterpret_cast<const f16x8*>(&Alds[(16 + lr) * 40 + lq * 8]);
#pragma unroll
        for (int t = 0; t < 5; t++) {
            const f16x8 b = *reinterpret_cast<const f16x8*>(
                &Bt[((w * 5 + t) * 16 + lr) * 40 + lq * 8]);
            acc[0][t] = __builtin_amdgcn_mfma_f32_16x16x32_f16(a0, b, acc[0][t], 0, 0, 0);
            acc[1][t] = __builtin_amdgcn_mfma_f32_16x16x32_f16(a1, b, acc[1][t], 0, 0, 0);
        }
    }
    // ---- bias + lrelu, direct x3 store (quarter-coalesced), run-length pooled
#pragma unroll
    for (int t = 0; t < 5; t++) {
        int col = w * 80 + t * 16 + lr;
        float bj = bias[col];
        float run = 0.f;
        int g = bt[lq * 4];
#pragma unroll
        for (int mt = 0; mt < 2; mt++)
#pragma unroll
            for (int j = 0; j < 4; j++) {
                int row = mt * 16 + lq * 4 + j;
                bool ok = base + row < NN;
                float vv = lrelu(acc[mt][t][j] + bj, 0.01f);
                if (ok) x3[(size_t)(base + row) * HC + col] = vv;
                int gb = bt[row];
                if (gb != g) { atomicAdd(&psum[g * HC + col], run); run = 0.f; g = gb; }
                if (ok) run += vv;
            }
        atomicAdd(&psum[g * HC + col], run);
    }
}

__global__ void pooldiv_kernel(const float* __restrict__ psum, const int* __restrict__ gcnt,
                               float* pooled_out) {
    int i = blockIdx.x * 256 + threadIdx.x;
    if (i < NG * HC) pooled_out[i] = psum[i] / fmaxf((float)gcnt[i / HC], 1.f);
}

// ---------------------------------------------------------------------- launch
extern "C" void kernel_launch(void* const* d_in, const int* in_sizes, int n_in,
                              void* d_out, int out_size, void* d_ws, size_t ws_size,
                              hipStream_t stream) {
    const float* x    = (const float*)d_in[0];
    const int*   ei   = (const int*)d_in[1];
    const float* ea   = (const float*)d_in[2];
    const int*   batch= (const int*)d_in[3];
    const float* w1   = (const float*)d_in[4];
    const float* we1  = (const float*)d_in[5];
    const float* as1  = (const float*)d_in[6];
    const float* ad1  = (const float*)d_in[7];
    const float* ae1  = (const float*)d_in[8];
    const float* b1   = (const float*)d_in[9];
    const float* w2   = (const float*)d_in[10];
    const float* we2  = (const float*)d_in[11];
    const float* as2  = (const float*)d_in[12];
    const float* ad2  = (const float*)d_in[13];
    const float* ae2  = (const float*)d_in[14];
    const float* b2   = (const float*)d_in[15];
    const float* ln1g = (const float*)d_in[16];
    const float* ln1b = (const float*)d_in[17];
    const float* ln2g = (const float*)d_in[18];
    const float* ln2b = (const float*)d_in[19];
    const float* mw   = (const float*)d_in[20];
    const float* mb   = (const float*)d_in[21];

    float* out = (float*)d_out;
    float* pooled_out = out + (size_t)NN * HC;
    float* a1 = pooled_out + NG * HC;
    float* a2 = a1 + (size_t)(EE + NN) * NH;

    char* wp = (char*)d_ws;
    auto alloc = [&](size_t bytes) {
        void* p = (void*)wp;
        wp += (bytes + 255) & ~(size_t)255;
        return p;
    };
    // 32MB region, triple-overlaid in time:
    //   [0..8)   hist_g   (dead after sscan)     -> [0..16)  h fp16
    //   [8..24)  base_g   (dead after scatter)   -> [16..32) x12h fp16
    char* region = (char*)alloc(32 * 1024 * 1024);
    __half* hbuf = (__half*)region;                               // 16 MB fp16 h
    __half* x12h = (__half*)(region + 16 * 1024 * 1024);          // 16 MB fp16 x1/x2
    unsigned*       hist_g = (unsigned*)region;                   // 8 MB
    unsigned short* base_g = (unsigned short*)(region + 8 * 1024 * 1024); // 16 MB
    uint4* erec  = (uint4*)alloc((size_t)EE * 16);       // 12.8 MB
    float* als   = (float*)alloc((size_t)NN * ALS8 * 4); // padded al_s
    float* ald   = (float*)alloc((size_t)NN * NH * 4);
    int*   deg   = (int*)alloc((size_t)NN * 4);
    int*   soff  = (int*)alloc((size_t)(NN + 1) * 4);
    float* sbuf  = (float*)alloc(64);
    float* psum  = (float*)alloc((size_t)NG * HC * 4);
    int*   gcnt  = (int*)alloc((size_t)NG * 4);
    int*   bsum  = (int*)alloc(256 * 4);
    int*   boff  = (int*)alloc(256 * 4);
    __half* wt1  = (__half*)alloc((size_t)160 * 128 * 2);  // W^T fp16 per layer
    __half* wt2  = (__half*)alloc((size_t)160 * 160 * 2);
    __half* wt3  = (__half*)alloc((size_t)160 * 160 * 2);

    prep_kernel<<<40, 256, 0, stream>>>(batch, psum, gcnt, we1, ae1, we2, ae2, sbuf);
    prepw_kernel<<<100, 256, 0, stream>>>(w1, w2, mw, wt1, wt2, wt3);
    hist_kernel<<<NB, 256, 0, stream>>>(ei, hist_g);
    sscan_kernel<<<49, 256, 0, stream>>>(hist_g, base_g, deg);
    scan1_kernel<<<196, 256, 0, stream>>>(deg, bsum);
    scan2_kernel<<<1, 256, 0, stream>>>(bsum, boff);
    scan3_kernel<<<196, 256, 0, stream>>>(deg, boff, soff);
    scatter_kernel<<<NB, 256, 0, stream>>>(ei, ea, base_g, soff, erec);

    const int GB = (NN + 31) / 32;   // 1563 gemm blocks

    gemm_kernel<128, float><<<GB, 128, 0, stream>>>(x, wt1, as1, ad1, hbuf, als, ald);
    aggregate_kernel<<<12500, 256, 0, stream>>>(soff, erec, hbuf, als, ald,
                                                sbuf, b1, ln1g, ln1b, a1, x12h);

    gemm_kernel<160, __half><<<GB, 128, 0, stream>>>(x12h, wt2, as2, ad2, hbuf, als, ald);
    aggregate_kernel<<<12500, 256, 0, stream>>>(soff, erec, hbuf, als, ald,
                                                sbuf + 5, b2, ln2g, ln2b, a2, x12h);

    gemm3_kernel<<<GB, 128, 0, stream>>>(x12h, wt3, mb, batch, out, psum);
    pooldiv_kernel<<<40, 256, 0, stream>>>(psum, gcnt, pooled_out);
}